// Round 1
// baseline (1514.093 us; speedup 1.0000x reference)
//
#include <hip/hip_runtime.h>
#include <hip/hip_bf16.h>
#include <stdint.h>

// ---- problem constants ----
#define B_      2
#define N_      2048
#define S_      2049          // tokens incl. cls
#define SP_     2112          // padded tokens per batch (33*64)
#define MP_     (B_*SP_)      // 4224 = 33*128
#define IN_DIM_ 1024
#define DIM_    512
#define HEADS_  8
#define DH_     128
#define INNER_  1024
#define MLP_    1024
#define DEPTH_  4

typedef __bf16 bf16;
typedef __bf16 bf16x8 __attribute__((ext_vector_type(8)));
typedef float  f32x4  __attribute__((ext_vector_type(4)));

// ---------------------------------------------------------------------------
// Weight convert + transpose: src [L][K][N] f32 -> dst [L][N][K] bf16
// ---------------------------------------------------------------------------
__global__ __launch_bounds__(256) void wconv_kernel(const float* __restrict__ src,
                                                    bf16* __restrict__ dst,
                                                    int K, int N)
{
    __shared__ float tile[32][33];
    size_t mo = (size_t)blockIdx.z * K * N;
    int n0 = blockIdx.x * 32, k0 = blockIdx.y * 32;
    int tx = threadIdx.x & 31, ty = threadIdx.x >> 5;   // 32 x 8
#pragma unroll
    for (int i = 0; i < 32; i += 8)
        tile[ty + i][tx] = src[mo + (size_t)(k0 + ty + i) * N + n0 + tx];
    __syncthreads();
#pragma unroll
    for (int i = 0; i < 32; i += 8)
        dst[mo + (size_t)(n0 + ty + i) * K + k0 + tx] = (bf16)tile[tx][ty + i];
}

// ---------------------------------------------------------------------------
// x (B,N,IN) f32 -> x_bf (B,SP,IN) bf16 with row 0 + pad rows zeroed
// ---------------------------------------------------------------------------
__global__ __launch_bounds__(256) void xconv_kernel(const float* __restrict__ x,
                                                    bf16* __restrict__ xb)
{
    int idx = blockIdx.x * 256 + threadIdx.x;    // MP_*IN_DIM_/8 items
    int row = idx >> 7;                          // IN_DIM_/8 = 128 groups/row
    int c   = (idx & 127) * 8;
    int b = row / SP_, s = row - b * SP_;
    bf16x8 v;
    if (s >= 1 && s <= N_) {
        const float* src = x + (size_t)(b * N_ + s - 1) * IN_DIM_ + c;
#pragma unroll
        for (int i = 0; i < 8; ++i) v[i] = (bf16)src[i];
    } else {
#pragma unroll
        for (int i = 0; i < 8; ++i) v[i] = (bf16)0.f;
    }
    *(bf16x8*)&xb[(size_t)row * IN_DIM_ + c] = v;
}

// ---------------------------------------------------------------------------
// cls token -> h row 0 of each batch (f32)
// ---------------------------------------------------------------------------
__global__ void cls_kernel(const float* __restrict__ cls, float* __restrict__ h)
{
    h[(size_t)(blockIdx.x * SP_) * DIM_ + threadIdx.x] = cls[threadIdx.x];
}

// ---------------------------------------------------------------------------
// LayerNorm over DIM_=512, one wave per row, f32 in -> bf16 out
// ---------------------------------------------------------------------------
__global__ __launch_bounds__(256) void ln_kernel(const float* __restrict__ h,
                                                 const float* __restrict__ g,
                                                 const float* __restrict__ bta,
                                                 bf16* __restrict__ out)
{
    int row  = blockIdx.x * 4 + (threadIdx.x >> 6);
    int lane = threadIdx.x & 63;
    const float* x = h + (size_t)row * DIM_;
    float v[8]; float s = 0.f;
#pragma unroll
    for (int i = 0; i < 8; ++i) { v[i] = x[lane + 64 * i]; s += v[i]; }
#pragma unroll
    for (int o = 32; o; o >>= 1) s += __shfl_xor(s, o);
    float mean = s * (1.f / DIM_);
    float vs = 0.f;
#pragma unroll
    for (int i = 0; i < 8; ++i) { float d = v[i] - mean; vs += d * d; }
#pragma unroll
    for (int o = 32; o; o >>= 1) vs += __shfl_xor(vs, o);
    float rstd = rsqrtf(vs * (1.f / DIM_) + 1e-5f);
    bf16* orow = out + (size_t)row * DIM_;
#pragma unroll
    for (int i = 0; i < 8; ++i)
        orow[lane + 64 * i] = (bf16)((v[i] - mean) * rstd * g[lane + 64 * i] + bta[lane + 64 * i]);
}

// ---------------------------------------------------------------------------
// GEMM: C[M][N] = act(A[M][K] * Bt[N][K]^T + bias), bf16 inputs, fp32 acc
// 128x128 tile, BK=64, 256 threads (2x2 waves of 64x64)
// ACT: 0=none 1=relu 2=gelu(exact). OUTBF: 1 -> bf16 out, 0 -> f32 out.
// ---------------------------------------------------------------------------
template<int ACT, int OUTBF>
__global__ __launch_bounds__(256) void gemm_bt(const bf16* __restrict__ A,
                                               const bf16* __restrict__ Bt,
                                               const float* __restrict__ bias,
                                               void* __restrict__ Cp,
                                               int M, int N, int K)
{
    __shared__ __align__(16) bf16 As[128][64];
    __shared__ __align__(16) bf16 Bs[128][64];
    const int tid  = threadIdx.x;
    const int wave = tid >> 6, lane = tid & 63;
    const int bm = blockIdx.x * 128, bn = blockIdx.y * 128;
    const int wr = (wave >> 1) * 64, wc = (wave & 1) * 64;

    f32x4 acc[4][4];
#pragma unroll
    for (int m = 0; m < 4; ++m)
#pragma unroll
        for (int n = 0; n < 4; ++n) acc[m][n] = (f32x4){0.f, 0.f, 0.f, 0.f};

    for (int k0 = 0; k0 < K; k0 += 64) {
#pragma unroll
        for (int t = 0; t < 4; ++t) {
            int e = (t * 256 + tid) * 8;
            int r = e >> 6, c = e & 63;
            *(bf16x8*)&As[r][c] = *(const bf16x8*)&A[(size_t)(bm + r) * K + k0 + c];
            *(bf16x8*)&Bs[r][c] = *(const bf16x8*)&Bt[(size_t)(bn + r) * K + k0 + c];
        }
        __syncthreads();
        const int fr = lane & 15, fk = (lane >> 4) * 8;
#pragma unroll
        for (int kk = 0; kk < 2; ++kk) {
            bf16x8 af[4], bb[4];
#pragma unroll
            for (int m = 0; m < 4; ++m) af[m] = *(const bf16x8*)&As[wr + m * 16 + fr][kk * 32 + fk];
#pragma unroll
            for (int n = 0; n < 4; ++n) bb[n] = *(const bf16x8*)&Bs[wc + n * 16 + fr][kk * 32 + fk];
#pragma unroll
            for (int m = 0; m < 4; ++m)
#pragma unroll
                for (int n = 0; n < 4; ++n)
                    acc[m][n] = __builtin_amdgcn_mfma_f32_16x16x32_bf16(af[m], bb[n], acc[m][n], 0, 0, 0);
        }
        __syncthreads();
    }

    const int fc = lane & 15, fr4 = (lane >> 4) * 4;
#pragma unroll
    for (int n = 0; n < 4; ++n) {
        int col = bn + wc + n * 16 + fc;
        float bv = bias ? bias[col] : 0.f;
#pragma unroll
        for (int m = 0; m < 4; ++m) {
#pragma unroll
            for (int j = 0; j < 4; ++j) {
                int row = bm + wr + m * 16 + fr4 + j;
                float v = acc[m][n][j] + bv;
                if (ACT == 1) v = fmaxf(v, 0.f);
                if (ACT == 2) v = 0.5f * v * (1.f + erff(v * 0.70710678118654752f));
                if (OUTBF) ((bf16*)Cp)[(size_t)row * N + col] = (bf16)v;
                else       ((float*)Cp)[(size_t)row * N + col] = v;
            }
        }
    }
}

// ---------------------------------------------------------------------------
// Flash attention: grid (B*HEADS, SP_/64). 256 threads = 4 waves, each wave
// owns 16 q-rows. KV tiles of 64. qkv rows: [q(1024)|k(1024)|v(1024)].
// ---------------------------------------------------------------------------
__global__ __launch_bounds__(256) void attn_kernel(const bf16* __restrict__ qkv,
                                                   const float* __restrict__ mask,
                                                   bf16* __restrict__ o)
{
    __shared__ __align__(16) bf16 Qs[64][128];
    __shared__ __align__(16) bf16 Ks[64][128];
    __shared__ __align__(16) bf16 Vt[128][64];
    __shared__ __align__(16) bf16 Ps[4][16][64];

    const int bh = blockIdx.x;
    const int b = bh >> 3, hh = bh & 7;
    const int q0 = blockIdx.y * 64;
    const int tid = threadIdx.x, wave = tid >> 6, lane = tid & 63;

    const bf16* qb = qkv + (size_t)(b * SP_) * (3 * INNER_) + hh * DH_;
    const bf16* kb = qb + INNER_;
    const bf16* vb = qb + 2 * INNER_;

#pragma unroll
    for (int t = 0; t < 4; ++t) {
        int e = (t * 256 + tid) * 8;
        int r = e >> 7, c = e & 127;
        *(bf16x8*)&Qs[r][c] = *(const bf16x8*)&qb[(size_t)(q0 + r) * (3 * INNER_) + c];
    }

    const int fc  = lane & 15;
    const int fk8 = (lane >> 4) * 8;
    const int rr0 = (lane >> 4) * 4;

    f32x4 accO[8];
#pragma unroll
    for (int f = 0; f < 8; ++f) accO[f] = (f32x4){0.f, 0.f, 0.f, 0.f};
    float mrow[4] = {-1e30f, -1e30f, -1e30f, -1e30f};
    float lrow[4] = {0.f, 0.f, 0.f, 0.f};
    const float scale = 0.08838834764831845f;   // 1/sqrt(128)

    for (int kt = 0; kt < SP_ / 64; ++kt) {
        int j0 = kt * 64;
        __syncthreads();   // previous tile fully consumed (also covers Q staging)
#pragma unroll
        for (int t = 0; t < 4; ++t) {
            int e = (t * 256 + tid) * 8;
            int r = e >> 7, c = e & 127;
            *(bf16x8*)&Ks[r][c] = *(const bf16x8*)&kb[(size_t)(j0 + r) * (3 * INNER_) + c];
        }
#pragma unroll
        for (int t = 0; t < 4; ++t) {
            int idx = t * 256 + tid;
            int j = idx & 63;
            int d0 = (idx >> 6) * 8;
            bf16x8 v = *(const bf16x8*)&vb[(size_t)(j0 + j) * (3 * INNER_) + d0];
#pragma unroll
            for (int i = 0; i < 8; ++i) Vt[d0 + i][j] = v[i];
        }
        __syncthreads();

        // S = Q K^T for this wave's 16 q-rows x 64 kv-cols
        f32x4 sf[4];
#pragma unroll
        for (int f = 0; f < 4; ++f) sf[f] = (f32x4){0.f, 0.f, 0.f, 0.f};
#pragma unroll
        for (int kk = 0; kk < 4; ++kk) {
            bf16x8 aq = *(const bf16x8*)&Qs[wave * 16 + fc][kk * 32 + fk8];
#pragma unroll
            for (int f = 0; f < 4; ++f) {
                bf16x8 bk = *(const bf16x8*)&Ks[f * 16 + fc][kk * 32 + fk8];
                sf[f] = __builtin_amdgcn_mfma_f32_16x16x32_bf16(aq, bk, sf[f], 0, 0, 0);
            }
        }
        // scale + mask
#pragma unroll
        for (int f = 0; f < 4; ++f) {
            int jc = j0 + f * 16 + fc;
            bool keep = (jc < S_) && (jc == 0 || mask[(size_t)b * N_ + jc - 1] != 0.f);
            float bia = keep ? 0.f : -1e30f;
#pragma unroll
            for (int r = 0; r < 4; ++r) sf[f][r] = sf[f][r] * scale + bia;
        }
        // per-row tile max (cols are spread over the 16-lane group + 4 frags)
        float rmax[4];
#pragma unroll
        for (int r = 0; r < 4; ++r)
            rmax[r] = fmaxf(fmaxf(sf[0][r], sf[1][r]), fmaxf(sf[2][r], sf[3][r]));
#pragma unroll
        for (int off = 1; off < 16; off <<= 1)
#pragma unroll
            for (int r = 0; r < 4; ++r) rmax[r] = fmaxf(rmax[r], __shfl_xor(rmax[r], off));
        float corr[4];
#pragma unroll
        for (int r = 0; r < 4; ++r) {
            float mn = fmaxf(mrow[r], rmax[r]);
            corr[r]  = __expf(mrow[r] - mn);
            mrow[r]  = mn;
            lrow[r] *= corr[r];
        }
#pragma unroll
        for (int f = 0; f < 8; ++f)
#pragma unroll
            for (int r = 0; r < 4; ++r) accO[f][r] *= corr[r];
        // P = exp(S - m) -> per-wave LDS (bf16), accumulate partial row sums
#pragma unroll
        for (int f = 0; f < 4; ++f) {
#pragma unroll
            for (int r = 0; r < 4; ++r) {
                float pv = __expf(sf[f][r] - mrow[r]);
                lrow[r] += pv;
                Ps[wave][rr0 + r][f * 16 + fc] = (bf16)pv;
            }
        }
        // O += P * V   (A frag rows = q-rows, k = kv index; B = Vt)
#pragma unroll
        for (int kk = 0; kk < 2; ++kk) {
            bf16x8 ap = *(const bf16x8*)&Ps[wave][fc][kk * 32 + fk8];
#pragma unroll
            for (int f = 0; f < 8; ++f) {
                bf16x8 bv = *(const bf16x8*)&Vt[f * 16 + fc][kk * 32 + fk8];
                accO[f] = __builtin_amdgcn_mfma_f32_16x16x32_bf16(ap, bv, accO[f], 0, 0, 0);
            }
        }
    }

    // finish l (sum over the 16 column-lanes) and write O
#pragma unroll
    for (int off = 1; off < 16; off <<= 1)
#pragma unroll
        for (int r = 0; r < 4; ++r) lrow[r] += __shfl_xor(lrow[r], off);
    float linv[4];
#pragma unroll
    for (int r = 0; r < 4; ++r) linv[r] = lrow[r] > 0.f ? 1.f / lrow[r] : 0.f;

#pragma unroll
    for (int f = 0; f < 8; ++f) {
        int col = hh * DH_ + f * 16 + fc;
#pragma unroll
        for (int r = 0; r < 4; ++r) {
            int row = q0 + wave * 16 + rr0 + r;
            o[(size_t)(b * SP_ + row) * INNER_ + col] = (bf16)(accO[f][r] * linv[r]);
        }
    }
}

// ---------------------------------------------------------------------------
// Head: pooled = h[:,0]; LN(norm) -> LN(head_ln) -> @ head_w + head_b
// one wave per batch element
// ---------------------------------------------------------------------------
__global__ __launch_bounds__(64) void head_kernel(const float* __restrict__ h,
                                                  const float* __restrict__ ng, const float* __restrict__ nb,
                                                  const float* __restrict__ hg, const float* __restrict__ hb,
                                                  const float* __restrict__ hw, const float* __restrict__ hbi,
                                                  float* __restrict__ out)
{
    int b = blockIdx.x, lane = threadIdx.x;
    const float* xr = h + (size_t)(b * SP_) * DIM_;
    float v[8]; float s = 0.f;
#pragma unroll
    for (int i = 0; i < 8; ++i) { v[i] = xr[lane + 64 * i]; s += v[i]; }
#pragma unroll
    for (int o = 32; o; o >>= 1) s += __shfl_xor(s, o);
    float mean = s * (1.f / DIM_); float vs = 0.f;
#pragma unroll
    for (int i = 0; i < 8; ++i) { float d = v[i] - mean; vs += d * d; }
#pragma unroll
    for (int o = 32; o; o >>= 1) vs += __shfl_xor(vs, o);
    float rstd = rsqrtf(vs * (1.f / DIM_) + 1e-5f);
#pragma unroll
    for (int i = 0; i < 8; ++i) v[i] = (v[i] - mean) * rstd * ng[lane + 64 * i] + nb[lane + 64 * i];
    // second LN
    s = 0.f;
#pragma unroll
    for (int i = 0; i < 8; ++i) s += v[i];
#pragma unroll
    for (int o = 32; o; o >>= 1) s += __shfl_xor(s, o);
    mean = s * (1.f / DIM_); vs = 0.f;
#pragma unroll
    for (int i = 0; i < 8; ++i) { float d = v[i] - mean; vs += d * d; }
#pragma unroll
    for (int o = 32; o; o >>= 1) vs += __shfl_xor(vs, o);
    rstd = rsqrtf(vs * (1.f / DIM_) + 1e-5f);
#pragma unroll
    for (int i = 0; i < 8; ++i) v[i] = (v[i] - mean) * rstd * hg[lane + 64 * i] + hb[lane + 64 * i];
    // head matmul 512x2
    float a0 = 0.f, a1 = 0.f;
#pragma unroll
    for (int i = 0; i < 8; ++i) {
        a0 += v[i] * hw[(lane + 64 * i) * 2 + 0];
        a1 += v[i] * hw[(lane + 64 * i) * 2 + 1];
    }
#pragma unroll
    for (int o = 32; o; o >>= 1) { a0 += __shfl_xor(a0, o); a1 += __shfl_xor(a1, o); }
    if (lane == 0) { out[b * 2 + 0] = a0 + hbi[0]; out[b * 2 + 1] = a1 + hbi[1]; }
}

// ---------------------------------------------------------------------------
extern "C" void kernel_launch(void* const* d_in, const int* in_sizes, int n_in,
                              void* d_out, int out_size, void* d_ws, size_t ws_size,
                              hipStream_t stream)
{
    const float* x       = (const float*)d_in[0];
    const float* mask    = (const float*)d_in[1];
    const float* proj_w  = (const float*)d_in[2];
    const float* proj_b  = (const float*)d_in[3];
    const float* cls_tok = (const float*)d_in[4];
    const float* ln1_g   = (const float*)d_in[5];
    const float* ln1_b   = (const float*)d_in[6];
    const float* qkv_w   = (const float*)d_in[7];
    const float* out_w   = (const float*)d_in[8];
    const float* out_b   = (const float*)d_in[9];
    const float* ln2_g   = (const float*)d_in[10];
    const float* ln2_b   = (const float*)d_in[11];
    const float* ff_w1   = (const float*)d_in[12];
    const float* ff_b1   = (const float*)d_in[13];
    const float* ff_w2   = (const float*)d_in[14];
    const float* ff_b2   = (const float*)d_in[15];
    const float* norm_g  = (const float*)d_in[16];
    const float* norm_b  = (const float*)d_in[17];
    const float* hln_g   = (const float*)d_in[18];
    const float* hln_b   = (const float*)d_in[19];
    const float* head_w  = (const float*)d_in[20];
    const float* head_b  = (const float*)d_in[21];

    char* p = (char*)d_ws;
    auto alloc = [&](size_t bytes) { char* r = p; p += (bytes + 255) & ~(size_t)255; return r; };
    bf16*  x_bf    = (bf16*)alloc((size_t)MP_ * IN_DIM_ * 2);
    float* h       = (float*)alloc((size_t)MP_ * DIM_ * 4);
    bf16*  hn_bf   = (bf16*)alloc((size_t)MP_ * DIM_ * 2);
    bf16*  qkv_bf  = (bf16*)alloc((size_t)MP_ * 3 * INNER_ * 2);
    bf16*  o_bf    = (bf16*)alloc((size_t)MP_ * INNER_ * 2);
    bf16*  ff1_bf  = (bf16*)alloc((size_t)MP_ * MLP_ * 2);
    bf16*  proj_wt = (bf16*)alloc((size_t)DIM_ * IN_DIM_ * 2);
    bf16*  qkv_wt  = (bf16*)alloc((size_t)DEPTH_ * 3 * INNER_ * DIM_ * 2);
    bf16*  out_wt  = (bf16*)alloc((size_t)DEPTH_ * DIM_ * INNER_ * 2);
    bf16*  ff1_wt  = (bf16*)alloc((size_t)DEPTH_ * MLP_ * DIM_ * 2);
    bf16*  ff2_wt  = (bf16*)alloc((size_t)DEPTH_ * DIM_ * MLP_ * 2);
    if ((size_t)(p - (char*)d_ws) > ws_size) return;  // fail visibly rather than corrupt

    // weights -> bf16 [N][K]
    wconv_kernel<<<dim3(DIM_ / 32, IN_DIM_ / 32, 1), 256, 0, stream>>>(proj_w, proj_wt, IN_DIM_, DIM_);
    wconv_kernel<<<dim3(3 * INNER_ / 32, DIM_ / 32, DEPTH_), 256, 0, stream>>>(qkv_w, qkv_wt, DIM_, 3 * INNER_);
    wconv_kernel<<<dim3(DIM_ / 32, INNER_ / 32, DEPTH_), 256, 0, stream>>>(out_w, out_wt, INNER_, DIM_);
    wconv_kernel<<<dim3(MLP_ / 32, DIM_ / 32, DEPTH_), 256, 0, stream>>>(ff_w1, ff1_wt, DIM_, MLP_);
    wconv_kernel<<<dim3(DIM_ / 32, MLP_ / 32, DEPTH_), 256, 0, stream>>>(ff_w2, ff2_wt, MLP_, DIM_);

    xconv_kernel<<<MP_ * IN_DIM_ / 8 / 256, 256, 0, stream>>>(x, x_bf);

    gemm_bt<1, 0><<<dim3(MP_ / 128, DIM_ / 128), 256, 0, stream>>>(x_bf, proj_wt, proj_b, h, MP_, DIM_, IN_DIM_);
    cls_kernel<<<B_, DIM_, 0, stream>>>(cls_tok, h);

    for (int l = 0; l < DEPTH_; ++l) {
        ln_kernel<<<MP_ / 4, 256, 0, stream>>>(h, ln1_g + l * DIM_, ln1_b + l * DIM_, hn_bf);
        gemm_bt<0, 1><<<dim3(MP_ / 128, 3 * INNER_ / 128), 256, 0, stream>>>(
            hn_bf, qkv_wt + (size_t)l * 3 * INNER_ * DIM_, nullptr, qkv_bf, MP_, 3 * INNER_, DIM_);
        attn_kernel<<<dim3(B_ * HEADS_, SP_ / 64), 256, 0, stream>>>(qkv_bf, mask, o_bf);
        gemm_bt<0, 0><<<dim3(MP_ / 128, DIM_ / 128), 256, 0, stream>>>(
            o_bf, out_wt + (size_t)l * DIM_ * INNER_, out_b + l * DIM_, h, MP_, DIM_, INNER_);
        ln_kernel<<<MP_ / 4, 256, 0, stream>>>(h, ln2_g + l * DIM_, ln2_b + l * DIM_, hn_bf);
        gemm_bt<2, 1><<<dim3(MP_ / 128, MLP_ / 128), 256, 0, stream>>>(
            hn_bf, ff1_wt + (size_t)l * MLP_ * DIM_, ff_b1 + l * MLP_, ff1_bf, MP_, MLP_, DIM_);
        gemm_bt<0, 0><<<dim3(MP_ / 128, DIM_ / 128), 256, 0, stream>>>(
            ff1_bf, ff2_wt + (size_t)l * DIM_ * MLP_, ff_b2 + l * DIM_, h, MP_, DIM_, MLP_);
    }

    head_kernel<<<B_, 64, 0, stream>>>(h, norm_g, norm_b, hln_g, hln_b, head_w, head_b, (float*)d_out);
}

// Round 2
// 1366.537 us; speedup vs baseline: 1.1080x; 1.1080x over previous
//
#include <hip/hip_runtime.h>
#include <hip/hip_bf16.h>
#include <stdint.h>

// ---- problem constants ----
#define B_      2
#define N_      2048
#define S_      2049          // tokens incl. cls
#define SP_     2176          // padded tokens per batch (17*128)
#define MP_     (B_*SP_)      // 4352 = 34*128
#define IN_DIM_ 1024
#define DIM_    512
#define HEADS_  8
#define DH_     128
#define INNER_  1024
#define MLP_    1024
#define DEPTH_  4
#define NKV_    (SP_/64)      // 34

typedef __bf16 bf16;
typedef __bf16 bf16x4 __attribute__((ext_vector_type(4)));
typedef __bf16 bf16x8 __attribute__((ext_vector_type(8)));
typedef float  f32x4  __attribute__((ext_vector_type(4)));

// XOR swizzle: spread 16B column slots across banks by row (G4 / T2)
__device__ __forceinline__ int sw64(int r, int c)  { return r*64  + (c ^ ((r&7)<<3)); }
__device__ __forceinline__ int sw128(int r, int c) { return r*128 + (c ^ ((r&7)<<3)); }

// ---------------------------------------------------------------------------
// Weight convert + transpose: src [L][K][N] f32 -> dst [L][N][K] bf16
// ---------------------------------------------------------------------------
__global__ __launch_bounds__(256) void wconv_kernel(const float* __restrict__ src,
                                                    bf16* __restrict__ dst,
                                                    int K, int N)
{
    __shared__ float tile[32][33];
    size_t mo = (size_t)blockIdx.z * K * N;
    int n0 = blockIdx.x * 32, k0 = blockIdx.y * 32;
    int tx = threadIdx.x & 31, ty = threadIdx.x >> 5;   // 32 x 8
#pragma unroll
    for (int i = 0; i < 32; i += 8)
        tile[ty + i][tx] = src[mo + (size_t)(k0 + ty + i) * N + n0 + tx];
    __syncthreads();
#pragma unroll
    for (int i = 0; i < 32; i += 8)
        dst[mo + (size_t)(n0 + ty + i) * K + k0 + tx] = (bf16)tile[tx][ty + i];
}

// ---------------------------------------------------------------------------
// x (B,N,IN) f32 -> x_bf (B,SP,IN) bf16 with row 0 + pad rows zeroed
// ---------------------------------------------------------------------------
__global__ __launch_bounds__(256) void xconv_kernel(const float* __restrict__ x,
                                                    bf16* __restrict__ xb)
{
    int idx = blockIdx.x * 256 + threadIdx.x;    // MP_*IN_DIM_/8 items
    int row = idx >> 7;                          // IN_DIM_/8 = 128 groups/row
    int c   = (idx & 127) * 8;
    int b = row / SP_, s = row - b * SP_;
    bf16x8 v;
    if (s >= 1 && s <= N_) {
        const float* src = x + (size_t)(b * N_ + s - 1) * IN_DIM_ + c;
#pragma unroll
        for (int i = 0; i < 8; ++i) v[i] = (bf16)src[i];
    } else {
#pragma unroll
        for (int i = 0; i < 8; ++i) v[i] = (bf16)0.f;
    }
    *(bf16x8*)&xb[(size_t)row * IN_DIM_ + c] = v;
}

// ---------------------------------------------------------------------------
// mask (B,N) -> additive bias pb (B,SP): 0 keep, -1e30 drop (cls always kept)
// ---------------------------------------------------------------------------
__global__ __launch_bounds__(256) void mask_kernel(const float* __restrict__ mask,
                                                   float* __restrict__ pb)
{
    int j = blockIdx.x * 256 + threadIdx.x;
    int b = blockIdx.y;
    if (j >= SP_) return;
    float v;
    if (j == 0) v = 0.f;
    else if (j <= N_) v = (mask[(size_t)b * N_ + j - 1] != 0.f) ? 0.f : -1e30f;
    else v = -1e30f;
    pb[(size_t)b * SP_ + j] = v;
}

// ---------------------------------------------------------------------------
// cls token -> h row 0 of each batch (f32)
// ---------------------------------------------------------------------------
__global__ void cls_kernel(const float* __restrict__ cls, float* __restrict__ h)
{
    h[(size_t)(blockIdx.x * SP_) * DIM_ + threadIdx.x] = cls[threadIdx.x];
}

// ---------------------------------------------------------------------------
// LayerNorm over DIM_=512, one wave per row, f32 in -> bf16 out
// ---------------------------------------------------------------------------
__global__ __launch_bounds__(256) void ln_kernel(const float* __restrict__ h,
                                                 const float* __restrict__ g,
                                                 const float* __restrict__ bta,
                                                 bf16* __restrict__ out)
{
    int row  = blockIdx.x * 4 + (threadIdx.x >> 6);
    int lane = threadIdx.x & 63;
    const float* x = h + (size_t)row * DIM_;
    float v[8]; float s = 0.f;
#pragma unroll
    for (int i = 0; i < 8; ++i) { v[i] = x[lane + 64 * i]; s += v[i]; }
#pragma unroll
    for (int o = 32; o; o >>= 1) s += __shfl_xor(s, o);
    float mean = s * (1.f / DIM_);
    float vs = 0.f;
#pragma unroll
    for (int i = 0; i < 8; ++i) { float d = v[i] - mean; vs += d * d; }
#pragma unroll
    for (int o = 32; o; o >>= 1) vs += __shfl_xor(vs, o);
    float rstd = rsqrtf(vs * (1.f / DIM_) + 1e-5f);
    bf16* orow = out + (size_t)row * DIM_;
#pragma unroll
    for (int i = 0; i < 8; ++i)
        orow[lane + 64 * i] = (bf16)((v[i] - mean) * rstd * g[lane + 64 * i] + bta[lane + 64 * i]);
}

// ---------------------------------------------------------------------------
// GEMM: C[M][N] = act(A[M][K] * Bt[N][K]^T + bias), bf16 in, fp32 acc.
// Tile BM x 128, BK=64, 256 threads. Swizzled LDS (conflict-free b128 reads).
// ---------------------------------------------------------------------------
template<int BM, int ACT, int OUTBF>
__global__ __launch_bounds__(256) void gemm_bt(const bf16* __restrict__ A,
                                               const bf16* __restrict__ Bt,
                                               const float* __restrict__ bias,
                                               void* __restrict__ Cp,
                                               int M, int N, int K)
{
    constexpr int MF = 4;
    constexpr int NF = (BM == 128) ? 4 : 2;
    __shared__ __align__(16) bf16 As[BM * 64];
    __shared__ __align__(16) bf16 Bs[128 * 64];
    const int tid  = threadIdx.x;
    const int wave = tid >> 6, lane = tid & 63;
    const int bm = blockIdx.x * BM, bn = blockIdx.y * 128;
    const int wr = (BM == 128) ? (wave >> 1) * 64 : 0;
    const int wc = (BM == 128) ? (wave & 1) * 64 : wave * 32;
    const int fr = lane & 15, fk = (lane >> 4) * 8;

    f32x4 acc[MF][NF];
#pragma unroll
    for (int m = 0; m < MF; ++m)
#pragma unroll
        for (int n = 0; n < NF; ++n) acc[m][n] = (f32x4){0.f, 0.f, 0.f, 0.f};

    for (int k0 = 0; k0 < K; k0 += 64) {
#pragma unroll
        for (int t = 0; t < BM / 32; ++t) {
            int e = (t * 256 + tid) * 8;
            int r = e >> 6, c = e & 63;
            *(bf16x8*)&As[sw64(r, c)] = *(const bf16x8*)&A[(size_t)(bm + r) * K + k0 + c];
        }
#pragma unroll
        for (int t = 0; t < 4; ++t) {
            int e = (t * 256 + tid) * 8;
            int r = e >> 6, c = e & 63;
            *(bf16x8*)&Bs[sw64(r, c)] = *(const bf16x8*)&Bt[(size_t)(bn + r) * K + k0 + c];
        }
        __syncthreads();
#pragma unroll
        for (int kk = 0; kk < 2; ++kk) {
            bf16x8 af[MF], bb[NF];
#pragma unroll
            for (int m = 0; m < MF; ++m) af[m] = *(const bf16x8*)&As[sw64(wr + m * 16 + fr, kk * 32 + fk)];
#pragma unroll
            for (int n = 0; n < NF; ++n) bb[n] = *(const bf16x8*)&Bs[sw64(wc + n * 16 + fr, kk * 32 + fk)];
#pragma unroll
            for (int m = 0; m < MF; ++m)
#pragma unroll
                for (int n = 0; n < NF; ++n)
                    acc[m][n] = __builtin_amdgcn_mfma_f32_16x16x32_bf16(af[m], bb[n], acc[m][n], 0, 0, 0);
        }
        __syncthreads();
    }

    const int fc = lane & 15, fr4 = (lane >> 4) * 4;
#pragma unroll
    for (int n = 0; n < NF; ++n) {
        int col = bn + wc + n * 16 + fc;
        float bv = bias ? bias[col] : 0.f;
#pragma unroll
        for (int m = 0; m < MF; ++m) {
#pragma unroll
            for (int j = 0; j < 4; ++j) {
                int row = bm + wr + m * 16 + fr4 + j;
                float v = acc[m][n][j] + bv;
                if (ACT == 1) v = fmaxf(v, 0.f);
                if (ACT == 2) v = 0.5f * v * (1.f + erff(v * 0.70710678118654752f));
                if (OUTBF) ((bf16*)Cp)[(size_t)row * N + col] = (bf16)v;
                else       ((float*)Cp)[(size_t)row * N + col] = v;
            }
        }
    }
}

// ---------------------------------------------------------------------------
// Flash attention v2: grid (B*HEADS, SP_/128). 256 thr = 4 waves x 32 q-rows.
// Swapped QK^T (S^T = K·Q^T), Q in regs, swizzled LDS, async K/V staging.
// ---------------------------------------------------------------------------
__global__ __launch_bounds__(256) void attn_kernel(const bf16* __restrict__ qkv,
                                                   const float* __restrict__ pb,
                                                   bf16* __restrict__ o)
{
    __shared__ __align__(16) bf16 Ks[64 * 128];     // [j][k] swizzled
    __shared__ __align__(16) bf16 Vt[128 * 64];     // [d][j] swizzled
    __shared__ __align__(16) bf16 Ps[4][32 * 64];   // per-wave [q][j] swizzled
    __shared__ float Msk[64];

    const int bh = blockIdx.x, b = bh >> 3, hh = bh & 7;
    const int q0 = blockIdx.y * 128;
    const int tid = threadIdx.x, wave = tid >> 6, lane = tid & 63;
    const int fc = lane & 15, g = lane >> 4, g8 = g * 8, rr0 = g * 4;

    const bf16* qb = qkv + (size_t)(b * SP_) * (3 * INNER_) + hh * DH_;
    const bf16* kb = qb + INNER_;
    const bf16* vb = qb + 2 * INNER_;

    // Q fragments in registers (used as B-operand: lane&15 = q, k = g*8+i)
    bf16x8 aq[2][4];
#pragma unroll
    for (int m = 0; m < 2; ++m)
#pragma unroll
        for (int kk = 0; kk < 4; ++kk)
            aq[m][kk] = *(const bf16x8*)&qb[(size_t)(q0 + wave * 32 + m * 16 + fc) * (3 * INNER_) + kk * 32 + g8];

    const int srow = tid >> 4;          // staging: row within 16-row stripe
    const int scol = (tid & 15) * 8;    // staging: 8-elem column
    bf16x8 kreg[4], vreg[4];
    float mreg;

    f32x4 accO[2][8];
#pragma unroll
    for (int m = 0; m < 2; ++m)
#pragma unroll
        for (int f = 0; f < 8; ++f) accO[m][f] = (f32x4){0.f, 0.f, 0.f, 0.f};
    float mrow[2] = {-3e38f, -3e38f};
    float lrow[2] = {0.f, 0.f};
    const float scale = 0.08838834764831845f;   // 1/sqrt(128)

    // issue global loads for tile kt into registers (T14 async stage)
    auto issue = [&](int kt) {
        int j0 = kt * 64;
#pragma unroll
        for (int t = 0; t < 4; ++t) {
            kreg[t] = *(const bf16x8*)&kb[(size_t)(j0 + t * 16 + srow) * (3 * INNER_) + scol];
            vreg[t] = *(const bf16x8*)&vb[(size_t)(j0 + t * 16 + srow) * (3 * INNER_) + scol];
        }
        mreg = pb[(size_t)b * SP_ + j0 + (tid & 63)];
    };

    issue(0);
    for (int kt = 0; kt < NKV_; ++kt) {
        __syncthreads();          // previous tile fully consumed
        {
#pragma unroll
            for (int t = 0; t < 4; ++t) {
                *(bf16x8*)&Ks[sw128(t * 16 + srow, scol)] = kreg[t];
#pragma unroll
                for (int i = 0; i < 8; ++i) Vt[sw64(scol + i, t * 16 + srow)] = vreg[t][i];
            }
            if (tid < 64) Msk[tid] = mreg;
        }
        __syncthreads();
        if (kt + 1 < NKV_) issue(kt + 1);   // loads fly under the compute below

        // ---- S^T = K · Q^T : lane holds S[j = f*16+rr0+r][q = m*16+fc] ----
        f32x4 sf[2][4];
#pragma unroll
        for (int m = 0; m < 2; ++m)
#pragma unroll
            for (int f = 0; f < 4; ++f) sf[m][f] = (f32x4){0.f, 0.f, 0.f, 0.f};
        __builtin_amdgcn_s_setprio(1);
#pragma unroll
        for (int kk = 0; kk < 4; ++kk) {
            bf16x8 bk[4];
#pragma unroll
            for (int f = 0; f < 4; ++f) bk[f] = *(const bf16x8*)&Ks[sw128(f * 16 + fc, kk * 32 + g8)];
#pragma unroll
            for (int m = 0; m < 2; ++m)
#pragma unroll
                for (int f = 0; f < 4; ++f)
                    sf[m][f] = __builtin_amdgcn_mfma_f32_16x16x32_bf16(bk[f], aq[m][kk], sf[m][f], 0, 0, 0);
        }
        __builtin_amdgcn_s_setprio(0);

        // ---- online softmax (per-q stats live at lane&15 = q) ----
        float rmax[2] = {-3e38f, -3e38f};
#pragma unroll
        for (int f = 0; f < 4; ++f) {
            f32x4 mb = *(const f32x4*)&Msk[f * 16 + rr0];
#pragma unroll
            for (int m = 0; m < 2; ++m)
#pragma unroll
                for (int r = 0; r < 4; ++r) {
                    float s = sf[m][f][r] * scale + mb[r];
                    sf[m][f][r] = s;
                    rmax[m] = fmaxf(rmax[m], s);
                }
        }
        float corr[2];
#pragma unroll
        for (int m = 0; m < 2; ++m) {
            rmax[m] = fmaxf(rmax[m], __shfl_xor(rmax[m], 16));
            rmax[m] = fmaxf(rmax[m], __shfl_xor(rmax[m], 32));
            float mn = fmaxf(mrow[m], rmax[m]);
            corr[m] = __expf(mrow[m] - mn);
            mrow[m] = mn;
            lrow[m] *= corr[m];
        }
        // P = exp(S - m) -> per-wave LDS (vectorized bf16x4 writes)
#pragma unroll
        for (int m = 0; m < 2; ++m)
#pragma unroll
            for (int f = 0; f < 4; ++f) {
                bf16x4 pw;
#pragma unroll
                for (int r = 0; r < 4; ++r) {
                    float p = __expf(sf[m][f][r] - mrow[m]);
                    lrow[m] += p;
                    pw[r] = (bf16)p;
                }
                *(bf16x4*)&Ps[wave][sw64(m * 16 + fc, f * 16 + rr0)] = pw;
            }
        // rescale accO (corr redistributed from q=lane&15 layout to row layout)
#pragma unroll
        for (int m = 0; m < 2; ++m) {
            float c0 = __shfl(corr[m], rr0 + 0);
            float c1 = __shfl(corr[m], rr0 + 1);
            float c2 = __shfl(corr[m], rr0 + 2);
            float c3 = __shfl(corr[m], rr0 + 3);
#pragma unroll
            for (int f = 0; f < 8; ++f) {
                accO[m][f][0] *= c0; accO[m][f][1] *= c1;
                accO[m][f][2] *= c2; accO[m][f][3] *= c3;
            }
        }
        // ---- O += P · V ----
        __builtin_amdgcn_s_setprio(1);
#pragma unroll
        for (int kk = 0; kk < 2; ++kk) {
            bf16x8 ap[2];
#pragma unroll
            for (int m = 0; m < 2; ++m) ap[m] = *(const bf16x8*)&Ps[wave][sw64(m * 16 + fc, kk * 32 + g8)];
#pragma unroll
            for (int f = 0; f < 8; ++f) {
                bf16x8 bv = *(const bf16x8*)&Vt[sw64(f * 16 + fc, kk * 32 + g8)];
#pragma unroll
                for (int m = 0; m < 2; ++m)
                    accO[m][f] = __builtin_amdgcn_mfma_f32_16x16x32_bf16(ap[m], bv, accO[m][f], 0, 0, 0);
            }
        }
        __builtin_amdgcn_s_setprio(0);
    }

    // ---- finalize: l-reduce over j-groups, redistribute, write O ----
#pragma unroll
    for (int m = 0; m < 2; ++m) {
        float l = lrow[m];
        l += __shfl_xor(l, 16);
        l += __shfl_xor(l, 32);
        float linv = (l > 0.f) ? 1.f / l : 0.f;
        float l0 = __shfl(linv, rr0 + 0);
        float l1 = __shfl(linv, rr0 + 1);
        float l2 = __shfl(linv, rr0 + 2);
        float l3 = __shfl(linv, rr0 + 3);
#pragma unroll
        for (int f = 0; f < 8; ++f) {
            int col = hh * DH_ + f * 16 + fc;
            size_t base = (size_t)(b * SP_ + q0 + wave * 32 + m * 16 + rr0) * INNER_ + col;
            o[base + 0 * INNER_] = (bf16)(accO[m][f][0] * l0);
            o[base + 1 * INNER_] = (bf16)(accO[m][f][1] * l1);
            o[base + 2 * INNER_] = (bf16)(accO[m][f][2] * l2);
            o[base + 3 * INNER_] = (bf16)(accO[m][f][3] * l3);
        }
    }
}

// ---------------------------------------------------------------------------
// Head: pooled = h[:,0]; LN(norm) -> LN(head_ln) -> @ head_w + head_b
// ---------------------------------------------------------------------------
__global__ __launch_bounds__(64) void head_kernel(const float* __restrict__ h,
                                                  const float* __restrict__ ng, const float* __restrict__ nb,
                                                  const float* __restrict__ hg, const float* __restrict__ hb,
                                                  const float* __restrict__ hw, const float* __restrict__ hbi,
                                                  float* __restrict__ out)
{
    int b = blockIdx.x, lane = threadIdx.x;
    const float* xr = h + (size_t)(b * SP_) * DIM_;
    float v[8]; float s = 0.f;
#pragma unroll
    for (int i = 0; i < 8; ++i) { v[i] = xr[lane + 64 * i]; s += v[i]; }
#pragma unroll
    for (int o = 32; o; o >>= 1) s += __shfl_xor(s, o);
    float mean = s * (1.f / DIM_); float vs = 0.f;
#pragma unroll
    for (int i = 0; i < 8; ++i) { float d = v[i] - mean; vs += d * d; }
#pragma unroll
    for (int o = 32; o; o >>= 1) vs += __shfl_xor(vs, o);
    float rstd = rsqrtf(vs * (1.f / DIM_) + 1e-5f);
#pragma unroll
    for (int i = 0; i < 8; ++i) v[i] = (v[i] - mean) * rstd * ng[lane + 64 * i] + nb[lane + 64 * i];
    s = 0.f;
#pragma unroll
    for (int i = 0; i < 8; ++i) s += v[i];
#pragma unroll
    for (int o = 32; o; o >>= 1) s += __shfl_xor(s, o);
    mean = s * (1.f / DIM_); vs = 0.f;
#pragma unroll
    for (int i = 0; i < 8; ++i) { float d = v[i] - mean; vs += d * d; }
#pragma unroll
    for (int o = 32; o; o >>= 1) vs += __shfl_xor(vs, o);
    rstd = rsqrtf(vs * (1.f / DIM_) + 1e-5f);
#pragma unroll
    for (int i = 0; i < 8; ++i) v[i] = (v[i] - mean) * rstd * hg[lane + 64 * i] + hb[lane + 64 * i];
    float a0 = 0.f, a1 = 0.f;
#pragma unroll
    for (int i = 0; i < 8; ++i) {
        a0 += v[i] * hw[(lane + 64 * i) * 2 + 0];
        a1 += v[i] * hw[(lane + 64 * i) * 2 + 1];
    }
#pragma unroll
    for (int o = 32; o; o >>= 1) { a0 += __shfl_xor(a0, o); a1 += __shfl_xor(a1, o); }
    if (lane == 0) { out[b * 2 + 0] = a0 + hbi[0]; out[b * 2 + 1] = a1 + hbi[1]; }
}

// ---------------------------------------------------------------------------
extern "C" void kernel_launch(void* const* d_in, const int* in_sizes, int n_in,
                              void* d_out, int out_size, void* d_ws, size_t ws_size,
                              hipStream_t stream)
{
    const float* x       = (const float*)d_in[0];
    const float* mask    = (const float*)d_in[1];
    const float* proj_w  = (const float*)d_in[2];
    const float* proj_b  = (const float*)d_in[3];
    const float* cls_tok = (const float*)d_in[4];
    const float* ln1_g   = (const float*)d_in[5];
    const float* ln1_b   = (const float*)d_in[6];
    const float* qkv_w   = (const float*)d_in[7];
    const float* out_w   = (const float*)d_in[8];
    const float* out_b   = (const float*)d_in[9];
    const float* ln2_g   = (const float*)d_in[10];
    const float* ln2_b   = (const float*)d_in[11];
    const float* ff_w1   = (const float*)d_in[12];
    const float* ff_b1   = (const float*)d_in[13];
    const float* ff_w2   = (const float*)d_in[14];
    const float* ff_b2   = (const float*)d_in[15];
    const float* norm_g  = (const float*)d_in[16];
    const float* norm_b  = (const float*)d_in[17];
    const float* hln_g   = (const float*)d_in[18];
    const float* hln_b   = (const float*)d_in[19];
    const float* head_w  = (const float*)d_in[20];
    const float* head_b  = (const float*)d_in[21];

    char* p = (char*)d_ws;
    auto alloc = [&](size_t bytes) { char* r = p; p += (bytes + 255) & ~(size_t)255; return r; };
    bf16*  x_bf    = (bf16*)alloc((size_t)MP_ * IN_DIM_ * 2);
    float* h       = (float*)alloc((size_t)MP_ * DIM_ * 4);
    bf16*  hn_bf   = (bf16*)alloc((size_t)MP_ * DIM_ * 2);
    bf16*  qkv_bf  = (bf16*)alloc((size_t)MP_ * 3 * INNER_ * 2);
    bf16*  o_bf    = (bf16*)alloc((size_t)MP_ * INNER_ * 2);
    bf16*  ff1_bf  = (bf16*)alloc((size_t)MP_ * MLP_ * 2);
    bf16*  proj_wt = (bf16*)alloc((size_t)DIM_ * IN_DIM_ * 2);
    bf16*  qkv_wt  = (bf16*)alloc((size_t)DEPTH_ * 3 * INNER_ * DIM_ * 2);
    bf16*  out_wt  = (bf16*)alloc((size_t)DEPTH_ * DIM_ * INNER_ * 2);
    bf16*  ff1_wt  = (bf16*)alloc((size_t)DEPTH_ * MLP_ * DIM_ * 2);
    bf16*  ff2_wt  = (bf16*)alloc((size_t)DEPTH_ * DIM_ * MLP_ * 2);
    float* pbias   = (float*)alloc((size_t)B_ * SP_ * 4);
    if ((size_t)(p - (char*)d_ws) > ws_size) return;

    // weights -> bf16 [N][K]
    wconv_kernel<<<dim3(DIM_ / 32, IN_DIM_ / 32, 1), 256, 0, stream>>>(proj_w, proj_wt, IN_DIM_, DIM_);
    wconv_kernel<<<dim3(3 * INNER_ / 32, DIM_ / 32, DEPTH_), 256, 0, stream>>>(qkv_w, qkv_wt, DIM_, 3 * INNER_);
    wconv_kernel<<<dim3(DIM_ / 32, INNER_ / 32, DEPTH_), 256, 0, stream>>>(out_w, out_wt, INNER_, DIM_);
    wconv_kernel<<<dim3(MLP_ / 32, DIM_ / 32, DEPTH_), 256, 0, stream>>>(ff_w1, ff1_wt, DIM_, MLP_);
    wconv_kernel<<<dim3(DIM_ / 32, MLP_ / 32, DEPTH_), 256, 0, stream>>>(ff_w2, ff2_wt, MLP_, DIM_);

    xconv_kernel<<<MP_ * IN_DIM_ / 8 / 256, 256, 0, stream>>>(x, x_bf);
    mask_kernel<<<dim3((SP_ + 255) / 256, B_), 256, 0, stream>>>(mask, pbias);

    gemm_bt<64, 1, 0><<<dim3(MP_ / 64, DIM_ / 128), 256, 0, stream>>>(x_bf, proj_wt, proj_b, h, MP_, DIM_, IN_DIM_);
    cls_kernel<<<B_, DIM_, 0, stream>>>(cls_tok, h);

    for (int l = 0; l < DEPTH_; ++l) {
        ln_kernel<<<MP_ / 4, 256, 0, stream>>>(h, ln1_g + l * DIM_, ln1_b + l * DIM_, hn_bf);
        gemm_bt<128, 0, 1><<<dim3(MP_ / 128, 3 * INNER_ / 128), 256, 0, stream>>>(
            hn_bf, qkv_wt + (size_t)l * 3 * INNER_ * DIM_, nullptr, qkv_bf, MP_, 3 * INNER_, DIM_);
        attn_kernel<<<dim3(B_ * HEADS_, SP_ / 128), 256, 0, stream>>>(qkv_bf, pbias, o_bf);
        gemm_bt<64, 0, 0><<<dim3(MP_ / 64, DIM_ / 128), 256, 0, stream>>>(
            o_bf, out_wt + (size_t)l * DIM_ * INNER_, out_b + l * DIM_, h, MP_, DIM_, INNER_);
        ln_kernel<<<MP_ / 4, 256, 0, stream>>>(h, ln2_g + l * DIM_, ln2_b + l * DIM_, hn_bf);
        gemm_bt<64, 2, 1><<<dim3(MP_ / 64, MLP_ / 128), 256, 0, stream>>>(
            hn_bf, ff1_wt + (size_t)l * MLP_ * DIM_, ff_b1 + l * MLP_, ff1_bf, MP_, MLP_, DIM_);
        gemm_bt<64, 0, 0><<<dim3(MP_ / 64, DIM_ / 128), 256, 0, stream>>>(
            ff1_bf, ff2_wt + (size_t)l * DIM_ * MLP_, ff_b2 + l * DIM_, h, MP_, DIM_, MLP_);
    }

    head_kernel<<<B_, 64, 0, stream>>>(h, norm_g, norm_b, hln_g, hln_b, head_w, head_b, (float*)d_out);
}

// Round 3
// 862.265 us; speedup vs baseline: 1.7559x; 1.5848x over previous
//
#include <hip/hip_runtime.h>
#include <hip/hip_bf16.h>
#include <stdint.h>

// ---- problem constants ----
#define B_      2
#define N_      2048
#define S_      2049          // tokens incl. cls
#define SP_     2176          // padded tokens per batch (17*128)
#define MP_     (B_*SP_)      // 4352 = 34*128
#define IN_DIM_ 1024
#define DIM_    512
#define HEADS_  8
#define DH_     128
#define INNER_  1024
#define MLP_    1024
#define DEPTH_  4
#define NKV_    (SP_/64)      // 34
#define NCHUNK_ 3
#define TPC_    12            // KV tiles per chunk (12,12,10)

typedef __bf16 bf16;
typedef __bf16 bf16x4 __attribute__((ext_vector_type(4)));
typedef __bf16 bf16x8 __attribute__((ext_vector_type(8)));
typedef float  f32x4  __attribute__((ext_vector_type(4)));

// XOR swizzles (G4/T2). swr: key = (r&7)^((r>>3)&7) so banks spread for BOTH
// row-varying (reads, r&7) and r>>3-varying (transpose writes) lane patterns.
__device__ __forceinline__ int sw64(int r, int c)  { return r*64  + (c ^ ((r&7)<<3)); }
__device__ __forceinline__ int sw128(int r, int c) { return r*128 + (c ^ ((r&7)<<3)); }
__device__ __forceinline__ int swr64(int r, int c) { return r*64  + (c ^ ((((r&7)^((r>>3)&7)))<<3)); }

// ---------------------------------------------------------------------------
// Weight convert + transpose: src [L][K][N] f32 -> dst [L][N][K] bf16
// ---------------------------------------------------------------------------
__global__ __launch_bounds__(256) void wconv_kernel(const float* __restrict__ src,
                                                    bf16* __restrict__ dst,
                                                    int K, int N)
{
    __shared__ float tile[32][33];
    size_t mo = (size_t)blockIdx.z * K * N;
    int n0 = blockIdx.x * 32, k0 = blockIdx.y * 32;
    int tx = threadIdx.x & 31, ty = threadIdx.x >> 5;   // 32 x 8
#pragma unroll
    for (int i = 0; i < 32; i += 8)
        tile[ty + i][tx] = src[mo + (size_t)(k0 + ty + i) * N + n0 + tx];
    __syncthreads();
#pragma unroll
    for (int i = 0; i < 32; i += 8)
        dst[mo + (size_t)(n0 + ty + i) * K + k0 + tx] = (bf16)tile[tx][ty + i];
}

// ---------------------------------------------------------------------------
// x (B,N,IN) f32 -> x_bf (B,SP,IN) bf16 with row 0 + pad rows zeroed
// ---------------------------------------------------------------------------
__global__ __launch_bounds__(256) void xconv_kernel(const float* __restrict__ x,
                                                    bf16* __restrict__ xb)
{
    int idx = blockIdx.x * 256 + threadIdx.x;    // MP_*IN_DIM_/8 items
    int row = idx >> 7;                          // IN_DIM_/8 = 128 groups/row
    int c   = (idx & 127) * 8;
    int b = row / SP_, s = row - b * SP_;
    bf16x8 v;
    if (s >= 1 && s <= N_) {
        const float* src = x + (size_t)(b * N_ + s - 1) * IN_DIM_ + c;
#pragma unroll
        for (int i = 0; i < 8; ++i) v[i] = (bf16)src[i];
    } else {
#pragma unroll
        for (int i = 0; i < 8; ++i) v[i] = (bf16)0.f;
    }
    *(bf16x8*)&xb[(size_t)row * IN_DIM_ + c] = v;
}

// ---------------------------------------------------------------------------
// mask (B,N) -> additive bias pb (B,SP): 0 keep, -1e30 drop (cls always kept)
// ---------------------------------------------------------------------------
__global__ __launch_bounds__(256) void mask_kernel(const float* __restrict__ mask,
                                                   float* __restrict__ pb)
{
    int j = blockIdx.x * 256 + threadIdx.x;
    int b = blockIdx.y;
    if (j >= SP_) return;
    float v;
    if (j == 0) v = 0.f;
    else if (j <= N_) v = (mask[(size_t)b * N_ + j - 1] != 0.f) ? 0.f : -1e30f;
    else v = -1e30f;
    pb[(size_t)b * SP_ + j] = v;
}

// ---------------------------------------------------------------------------
// cls token -> h row 0 of each batch (f32)
// ---------------------------------------------------------------------------
__global__ void cls_kernel(const float* __restrict__ cls, float* __restrict__ h)
{
    h[(size_t)(blockIdx.x * SP_) * DIM_ + threadIdx.x] = cls[threadIdx.x];
}

// ---------------------------------------------------------------------------
// LayerNorm over DIM_=512, one wave per row, f32 in -> bf16 out
// ---------------------------------------------------------------------------
__global__ __launch_bounds__(256) void ln_kernel(const float* __restrict__ h,
                                                 const float* __restrict__ g,
                                                 const float* __restrict__ bta,
                                                 bf16* __restrict__ out)
{
    int row  = blockIdx.x * 4 + (threadIdx.x >> 6);
    int lane = threadIdx.x & 63;
    const float* x = h + (size_t)row * DIM_;
    float v[8]; float s = 0.f;
#pragma unroll
    for (int i = 0; i < 8; ++i) { v[i] = x[lane + 64 * i]; s += v[i]; }
#pragma unroll
    for (int o = 32; o; o >>= 1) s += __shfl_xor(s, o);
    float mean = s * (1.f / DIM_);
    float vs = 0.f;
#pragma unroll
    for (int i = 0; i < 8; ++i) { float d = v[i] - mean; vs += d * d; }
#pragma unroll
    for (int o = 32; o; o >>= 1) vs += __shfl_xor(vs, o);
    float rstd = rsqrtf(vs * (1.f / DIM_) + 1e-5f);
    bf16* orow = out + (size_t)row * DIM_;
#pragma unroll
    for (int i = 0; i < 8; ++i)
        orow[lane + 64 * i] = (bf16)((v[i] - mean) * rstd * g[lane + 64 * i] + bta[lane + 64 * i]);
}

// ---------------------------------------------------------------------------
// GEMM: C[M][N] = act(A[M][K] * Bt[N][K]^T + bias), bf16 in, fp32 acc.
// Tile BM x 128, BK=64, 256 threads. Swizzled LDS (conflict-free b128 reads).
// ---------------------------------------------------------------------------
template<int BM, int ACT, int OUTBF>
__global__ __launch_bounds__(256) void gemm_bt(const bf16* __restrict__ A,
                                               const bf16* __restrict__ Bt,
                                               const float* __restrict__ bias,
                                               void* __restrict__ Cp,
                                               int M, int N, int K)
{
    constexpr int MF = 4;
    constexpr int NF = (BM == 128) ? 4 : 2;
    __shared__ __align__(16) bf16 As[BM * 64];
    __shared__ __align__(16) bf16 Bs[128 * 64];
    const int tid  = threadIdx.x;
    const int wave = tid >> 6, lane = tid & 63;
    const int bm = blockIdx.x * BM, bn = blockIdx.y * 128;
    const int wr = (BM == 128) ? (wave >> 1) * 64 : 0;
    const int wc = (BM == 128) ? (wave & 1) * 64 : wave * 32;
    const int fr = lane & 15, fk = (lane >> 4) * 8;

    f32x4 acc[MF][NF];
#pragma unroll
    for (int m = 0; m < MF; ++m)
#pragma unroll
        for (int n = 0; n < NF; ++n) acc[m][n] = (f32x4){0.f, 0.f, 0.f, 0.f};

    for (int k0 = 0; k0 < K; k0 += 64) {
#pragma unroll
        for (int t = 0; t < BM / 32; ++t) {
            int e = (t * 256 + tid) * 8;
            int r = e >> 6, c = e & 63;
            *(bf16x8*)&As[sw64(r, c)] = *(const bf16x8*)&A[(size_t)(bm + r) * K + k0 + c];
        }
#pragma unroll
        for (int t = 0; t < 4; ++t) {
            int e = (t * 256 + tid) * 8;
            int r = e >> 6, c = e & 63;
            *(bf16x8*)&Bs[sw64(r, c)] = *(const bf16x8*)&Bt[(size_t)(bn + r) * K + k0 + c];
        }
        __syncthreads();
#pragma unroll
        for (int kk = 0; kk < 2; ++kk) {
            bf16x8 af[MF], bb[NF];
#pragma unroll
            for (int m = 0; m < MF; ++m) af[m] = *(const bf16x8*)&As[sw64(wr + m * 16 + fr, kk * 32 + fk)];
#pragma unroll
            for (int n = 0; n < NF; ++n) bb[n] = *(const bf16x8*)&Bs[sw64(wc + n * 16 + fr, kk * 32 + fk)];
#pragma unroll
            for (int m = 0; m < MF; ++m)
#pragma unroll
                for (int n = 0; n < NF; ++n)
                    acc[m][n] = __builtin_amdgcn_mfma_f32_16x16x32_bf16(af[m], bb[n], acc[m][n], 0, 0, 0);
        }
        __syncthreads();
    }

    const int fc = lane & 15, fr4 = (lane >> 4) * 4;
#pragma unroll
    for (int n = 0; n < NF; ++n) {
        int col = bn + wc + n * 16 + fc;
        float bv = bias ? bias[col] : 0.f;
#pragma unroll
        for (int m = 0; m < MF; ++m) {
#pragma unroll
            for (int j = 0; j < 4; ++j) {
                int row = bm + wr + m * 16 + fr4 + j;
                float v = acc[m][n][j] + bv;
                if (ACT == 1) v = fmaxf(v, 0.f);
                if (ACT == 2) v = 0.5f * v * (1.f + erff(v * 0.70710678118654752f));
                if (OUTBF) ((bf16*)Cp)[(size_t)row * N + col] = (bf16)v;
                else       ((float*)Cp)[(size_t)row * N + col] = v;
            }
        }
    }
}

// ---------------------------------------------------------------------------
// Flash attention, KV-split: grid (B*HEADS, SP_/128, NCHUNK_). 4 waves x 32 q.
// Each chunk writes normalized partial O to its buffer + (m,l) to mlbuf.
// ---------------------------------------------------------------------------
__global__ __launch_bounds__(256) void attn_kernel(const bf16* __restrict__ qkv,
                                                   const float* __restrict__ pb,
                                                   bf16* __restrict__ o0,
                                                   bf16* __restrict__ o1,
                                                   bf16* __restrict__ o2,
                                                   float* __restrict__ mlbuf)
{
    __shared__ __align__(16) bf16 Ks[64 * 128];     // [j][k] swizzled
    __shared__ __align__(16) bf16 Vt[128 * 64];     // [d][j] swizzled (swr)
    __shared__ __align__(16) bf16 Ps[4][32 * 64];   // per-wave [q][j] swizzled (swr)
    __shared__ float Msk[64];

    const int bh = blockIdx.x, b = bh >> 3, hh = bh & 7;
    const int q0 = blockIdx.y * 128;
    const int chunk = blockIdx.z;
    const int t0 = chunk * TPC_;
    const int t1 = (t0 + TPC_ < NKV_) ? t0 + TPC_ : NKV_;
    bf16* obuf = (chunk == 0) ? o0 : (chunk == 1) ? o1 : o2;

    const int tid = threadIdx.x, wave = tid >> 6, lane = tid & 63;
    const int fc = lane & 15, g = lane >> 4, g8 = g * 8, rr0 = g * 4;

    const bf16* qb = qkv + (size_t)(b * SP_) * (3 * INNER_) + hh * DH_;
    const bf16* kb = qb + INNER_;
    const bf16* vb = qb + 2 * INNER_;

    // Q fragments in registers (B-operand: lane&15 = q, k = g*8+i)
    bf16x8 aq[2][4];
#pragma unroll
    for (int m = 0; m < 2; ++m)
#pragma unroll
        for (int kk = 0; kk < 4; ++kk)
            aq[m][kk] = *(const bf16x8*)&qb[(size_t)(q0 + wave * 32 + m * 16 + fc) * (3 * INNER_) + kk * 32 + g8];

    const int srow = tid >> 4;          // staging: row within 16-row stripe
    const int scol = (tid & 15) * 8;    // staging: 8-elem column
    bf16x8 kreg[4], vreg[4];
    float mreg;

    f32x4 accO[2][8];
#pragma unroll
    for (int m = 0; m < 2; ++m)
#pragma unroll
        for (int f = 0; f < 8; ++f) accO[m][f] = (f32x4){0.f, 0.f, 0.f, 0.f};
    float mrow[2] = {-3e38f, -3e38f};
    float lrow[2] = {0.f, 0.f};
    const float scale = 0.08838834764831845f;   // 1/sqrt(128)

    auto issue = [&](int kt) {          // T14 async stage: global -> regs
        int j0 = kt * 64;
#pragma unroll
        for (int t = 0; t < 4; ++t) {
            kreg[t] = *(const bf16x8*)&kb[(size_t)(j0 + t * 16 + srow) * (3 * INNER_) + scol];
            vreg[t] = *(const bf16x8*)&vb[(size_t)(j0 + t * 16 + srow) * (3 * INNER_) + scol];
        }
        mreg = pb[(size_t)b * SP_ + j0 + (tid & 63)];
    };

    issue(t0);
    for (int kt = t0; kt < t1; ++kt) {
        __syncthreads();          // previous tile fully consumed
        {
#pragma unroll
            for (int t = 0; t < 4; ++t) {
                *(bf16x8*)&Ks[sw128(t * 16 + srow, scol)] = kreg[t];
#pragma unroll
                for (int i = 0; i < 8; ++i) Vt[swr64(scol + i, t * 16 + srow)] = vreg[t][i];
            }
            if (tid < 64) Msk[tid] = mreg;
        }
        __syncthreads();
        if (kt + 1 < t1) issue(kt + 1);   // loads fly under the compute below

        // ---- S^T = K · Q^T : lane holds S[j = f*16+rr0+r][q = m*16+fc] ----
        f32x4 sf[2][4];
#pragma unroll
        for (int m = 0; m < 2; ++m)
#pragma unroll
            for (int f = 0; f < 4; ++f) sf[m][f] = (f32x4){0.f, 0.f, 0.f, 0.f};
        __builtin_amdgcn_s_setprio(1);
#pragma unroll
        for (int kk = 0; kk < 4; ++kk) {
            bf16x8 bk[4];
#pragma unroll
            for (int f = 0; f < 4; ++f) bk[f] = *(const bf16x8*)&Ks[sw128(f * 16 + fc, kk * 32 + g8)];
#pragma unroll
            for (int m = 0; m < 2; ++m)
#pragma unroll
                for (int f = 0; f < 4; ++f)
                    sf[m][f] = __builtin_amdgcn_mfma_f32_16x16x32_bf16(bk[f], aq[m][kk], sf[m][f], 0, 0, 0);
        }
        __builtin_amdgcn_s_setprio(0);

        // ---- online softmax (per-q stats live at lane&15 = q) ----
        float rmax[2] = {-3e38f, -3e38f};
#pragma unroll
        for (int f = 0; f < 4; ++f) {
            f32x4 mb = *(const f32x4*)&Msk[f * 16 + rr0];
#pragma unroll
            for (int m = 0; m < 2; ++m)
#pragma unroll
                for (int r = 0; r < 4; ++r) {
                    float s = sf[m][f][r] * scale + mb[r];
                    sf[m][f][r] = s;
                    rmax[m] = fmaxf(rmax[m], s);
                }
        }
        float corr[2];
#pragma unroll
        for (int m = 0; m < 2; ++m) {
            rmax[m] = fmaxf(rmax[m], __shfl_xor(rmax[m], 16));
            rmax[m] = fmaxf(rmax[m], __shfl_xor(rmax[m], 32));
            float mn = fmaxf(mrow[m], rmax[m]);
            corr[m] = __expf(mrow[m] - mn);
            mrow[m] = mn;
            lrow[m] *= corr[m];
        }
        // P = exp(S - m) -> per-wave LDS (vectorized bf16x4 writes)
#pragma unroll
        for (int m = 0; m < 2; ++m)
#pragma unroll
            for (int f = 0; f < 4; ++f) {
                bf16x4 pw;
#pragma unroll
                for (int r = 0; r < 4; ++r) {
                    float p = __expf(sf[m][f][r] - mrow[m]);
                    lrow[m] += p;
                    pw[r] = (bf16)p;
                }
                *(bf16x4*)&Ps[wave][swr64(m * 16 + fc, f * 16 + rr0)] = pw;
            }
        // rescale accO (corr redistributed from q=lane&15 layout to row layout)
#pragma unroll
        for (int m = 0; m < 2; ++m) {
            float c0 = __shfl(corr[m], rr0 + 0);
            float c1 = __shfl(corr[m], rr0 + 1);
            float c2 = __shfl(corr[m], rr0 + 2);
            float c3 = __shfl(corr[m], rr0 + 3);
#pragma unroll
            for (int f = 0; f < 8; ++f) {
                accO[m][f][0] *= c0; accO[m][f][1] *= c1;
                accO[m][f][2] *= c2; accO[m][f][3] *= c3;
            }
        }
        // ---- O += P · V ----
        __builtin_amdgcn_s_setprio(1);
#pragma unroll
        for (int kk = 0; kk < 2; ++kk) {
            bf16x8 ap[2];
#pragma unroll
            for (int m = 0; m < 2; ++m) ap[m] = *(const bf16x8*)&Ps[wave][swr64(m * 16 + fc, kk * 32 + g8)];
#pragma unroll
            for (int f = 0; f < 8; ++f) {
                bf16x8 bv = *(const bf16x8*)&Vt[swr64(f * 16 + fc, kk * 32 + g8)];
#pragma unroll
                for (int m = 0; m < 2; ++m)
                    accO[m][f] = __builtin_amdgcn_mfma_f32_16x16x32_bf16(ap[m], bv, accO[m][f], 0, 0, 0);
            }
        }
        __builtin_amdgcn_s_setprio(0);
    }

    // ---- finalize: l-reduce over j-groups, write normalized partial O + (m,l) ----
#pragma unroll
    for (int m = 0; m < 2; ++m) {
        float l = lrow[m];
        l += __shfl_xor(l, 16);
        l += __shfl_xor(l, 32);
        if (g == 0) {   // lanes 0..15 hold stats for q = base + fc
            int q = q0 + wave * 32 + m * 16 + fc;
            size_t mi = ((size_t)(chunk * B_ * HEADS_ + bh) * SP_ + q) * 2;
            mlbuf[mi + 0] = mrow[m];
            mlbuf[mi + 1] = l;
        }
        float linv = (l > 0.f) ? 1.f / l : 0.f;
        float l0 = __shfl(linv, rr0 + 0);
        float l1 = __shfl(linv, rr0 + 1);
        float l2 = __shfl(linv, rr0 + 2);
        float l3 = __shfl(linv, rr0 + 3);
#pragma unroll
        for (int f = 0; f < 8; ++f) {
            int col = hh * DH_ + f * 16 + fc;
            size_t base = (size_t)(b * SP_ + q0 + wave * 32 + m * 16 + rr0) * INNER_ + col;
            obuf[base + 0 * INNER_] = (bf16)(accO[m][f][0] * l0);
            obuf[base + 1 * INNER_] = (bf16)(accO[m][f][1] * l1);
            obuf[base + 2 * INNER_] = (bf16)(accO[m][f][2] * l2);
            obuf[base + 3 * INNER_] = (bf16)(accO[m][f][3] * l3);
        }
    }
}

// ---------------------------------------------------------------------------
// Combine KV-split partials: o_final = sum_c w_c * O_c, w_c = l_c*exp(m_c-M)/den
// grid (MP_*16/256, B*HEADS). o2 is read then overwritten elementwise (safe).
// ---------------------------------------------------------------------------
__global__ __launch_bounds__(256) void attn_combine_kernel(const bf16* __restrict__ o0,
                                                           const bf16* __restrict__ o1,
                                                           bf16* __restrict__ o2,
                                                           const float* __restrict__ mlbuf)
{
    const int bh = blockIdx.y, b = bh >> 3, hh = bh & 7;
    int gx = blockIdx.x * 256 + threadIdx.x;    // SP_ * 16 items per bh
    int q  = gx >> 4;
    int d  = (gx & 15) * 8;

    float m0, l0v, m1, l1v, m2, l2v;
    {
        size_t mi0 = ((size_t)(0 * B_ * HEADS_ + bh) * SP_ + q) * 2;
        size_t mi1 = ((size_t)(1 * B_ * HEADS_ + bh) * SP_ + q) * 2;
        size_t mi2 = ((size_t)(2 * B_ * HEADS_ + bh) * SP_ + q) * 2;
        m0 = mlbuf[mi0]; l0v = mlbuf[mi0 + 1];
        m1 = mlbuf[mi1]; l1v = mlbuf[mi1 + 1];
        m2 = mlbuf[mi2]; l2v = mlbuf[mi2 + 1];
    }
    float M = fmaxf(fmaxf(m0, m1), m2);
    float w0 = l0v * __expf(m0 - M);
    float w1 = l1v * __expf(m1 - M);
    float w2 = l2v * __expf(m2 - M);
    float den = w0 + w1 + w2;
    float r = (den > 0.f) ? 1.f / den : 0.f;
    w0 *= r; w1 *= r; w2 *= r;

    size_t base = (size_t)(b * SP_ + q) * INNER_ + hh * DH_ + d;
    bf16x8 v0 = *(const bf16x8*)&o0[base];
    bf16x8 v1 = *(const bf16x8*)&o1[base];
    bf16x8 v2 = *(const bf16x8*)&o2[base];
    bf16x8 out;
#pragma unroll
    for (int i = 0; i < 8; ++i)
        out[i] = (bf16)(w0 * (float)v0[i] + w1 * (float)v1[i] + w2 * (float)v2[i]);
    *(bf16x8*)&o2[base] = out;
}

// ---------------------------------------------------------------------------
// Head: pooled = h[:,0]; LN(norm) -> LN(head_ln) -> @ head_w + head_b
// ---------------------------------------------------------------------------
__global__ __launch_bounds__(64) void head_kernel(const float* __restrict__ h,
                                                  const float* __restrict__ ng, const float* __restrict__ nb,
                                                  const float* __restrict__ hg, const float* __restrict__ hb,
                                                  const float* __restrict__ hw, const float* __restrict__ hbi,
                                                  float* __restrict__ out)
{
    int b = blockIdx.x, lane = threadIdx.x;
    const float* xr = h + (size_t)(b * SP_) * DIM_;
    float v[8]; float s = 0.f;
#pragma unroll
    for (int i = 0; i < 8; ++i) { v[i] = xr[lane + 64 * i]; s += v[i]; }
#pragma unroll
    for (int o = 32; o; o >>= 1) s += __shfl_xor(s, o);
    float mean = s * (1.f / DIM_); float vs = 0.f;
#pragma unroll
    for (int i = 0; i < 8; ++i) { float d = v[i] - mean; vs += d * d; }
#pragma unroll
    for (int o = 32; o; o >>= 1) vs += __shfl_xor(vs, o);
    float rstd = rsqrtf(vs * (1.f / DIM_) + 1e-5f);
#pragma unroll
    for (int i = 0; i < 8; ++i) v[i] = (v[i] - mean) * rstd * ng[lane + 64 * i] + nb[lane + 64 * i];
    s = 0.f;
#pragma unroll
    for (int i = 0; i < 8; ++i) s += v[i];
#pragma unroll
    for (int o = 32; o; o >>= 1) s += __shfl_xor(s, o);
    mean = s * (1.f / DIM_); vs = 0.f;
#pragma unroll
    for (int i = 0; i < 8; ++i) { float d = v[i] - mean; vs += d * d; }
#pragma unroll
    for (int o = 32; o; o >>= 1) vs += __shfl_xor(vs, o);
    rstd = rsqrtf(vs * (1.f / DIM_) + 1e-5f);
#pragma unroll
    for (int i = 0; i < 8; ++i) v[i] = (v[i] - mean) * rstd * hg[lane + 64 * i] + hb[lane + 64 * i];
    float a0 = 0.f, a1 = 0.f;
#pragma unroll
    for (int i = 0; i < 8; ++i) {
        a0 += v[i] * hw[(lane + 64 * i) * 2 + 0];
        a1 += v[i] * hw[(lane + 64 * i) * 2 + 1];
    }
#pragma unroll
    for (int o = 32; o; o >>= 1) { a0 += __shfl_xor(a0, o); a1 += __shfl_xor(a1, o); }
    if (lane == 0) { out[b * 2 + 0] = a0 + hbi[0]; out[b * 2 + 1] = a1 + hbi[1]; }
}

// ---------------------------------------------------------------------------
extern "C" void kernel_launch(void* const* d_in, const int* in_sizes, int n_in,
                              void* d_out, int out_size, void* d_ws, size_t ws_size,
                              hipStream_t stream)
{
    const float* x       = (const float*)d_in[0];
    const float* mask    = (const float*)d_in[1];
    const float* proj_w  = (const float*)d_in[2];
    const float* proj_b  = (const float*)d_in[3];
    const float* cls_tok = (const float*)d_in[4];
    const float* ln1_g   = (const float*)d_in[5];
    const float* ln1_b   = (const float*)d_in[6];
    const float* qkv_w   = (const float*)d_in[7];
    const float* out_w   = (const float*)d_in[8];
    const float* out_b   = (const float*)d_in[9];
    const float* ln2_g   = (const float*)d_in[10];
    const float* ln2_b   = (const float*)d_in[11];
    const float* ff_w1   = (const float*)d_in[12];
    const float* ff_b1   = (const float*)d_in[13];
    const float* ff_w2   = (const float*)d_in[14];
    const float* ff_b2   = (const float*)d_in[15];
    const float* norm_g  = (const float*)d_in[16];
    const float* norm_b  = (const float*)d_in[17];
    const float* hln_g   = (const float*)d_in[18];
    const float* hln_b   = (const float*)d_in[19];
    const float* head_w  = (const float*)d_in[20];
    const float* head_b  = (const float*)d_in[21];

    char* p = (char*)d_ws;
    auto alloc = [&](size_t bytes) { char* r = p; p += (bytes + 255) & ~(size_t)255; return r; };
    bf16*  x_bf    = (bf16*)alloc((size_t)MP_ * IN_DIM_ * 2);   // dead after proj -> attn chunk0
    float* h       = (float*)alloc((size_t)MP_ * DIM_ * 4);
    bf16*  hn_bf   = (bf16*)alloc((size_t)MP_ * DIM_ * 2);      // dead during attn -> mlbuf
    bf16*  qkv_bf  = (bf16*)alloc((size_t)MP_ * 3 * INNER_ * 2);
    bf16*  o_bf    = (bf16*)alloc((size_t)MP_ * INNER_ * 2);    // attn chunk2 + final O
    bf16*  ff1_bf  = (bf16*)alloc((size_t)MP_ * MLP_ * 2);      // dead during attn -> chunk1
    bf16*  proj_wt = (bf16*)alloc((size_t)DIM_ * IN_DIM_ * 2);
    bf16*  qkv_wt  = (bf16*)alloc((size_t)DEPTH_ * 3 * INNER_ * DIM_ * 2);
    bf16*  out_wt  = (bf16*)alloc((size_t)DEPTH_ * DIM_ * INNER_ * 2);
    bf16*  ff1_wt  = (bf16*)alloc((size_t)DEPTH_ * MLP_ * DIM_ * 2);
    bf16*  ff2_wt  = (bf16*)alloc((size_t)DEPTH_ * DIM_ * MLP_ * 2);
    float* pbias   = (float*)alloc((size_t)B_ * SP_ * 4);
    if ((size_t)(p - (char*)d_ws) > ws_size) return;
    float* mlbuf = (float*)hn_bf;       // NCHUNK_*16*SP_*2 floats = 1.7 MB <= 4.45 MB

    // weights -> bf16 [N][K]
    wconv_kernel<<<dim3(DIM_ / 32, IN_DIM_ / 32, 1), 256, 0, stream>>>(proj_w, proj_wt, IN_DIM_, DIM_);
    wconv_kernel<<<dim3(3 * INNER_ / 32, DIM_ / 32, DEPTH_), 256, 0, stream>>>(qkv_w, qkv_wt, DIM_, 3 * INNER_);
    wconv_kernel<<<dim3(DIM_ / 32, INNER_ / 32, DEPTH_), 256, 0, stream>>>(out_w, out_wt, INNER_, DIM_);
    wconv_kernel<<<dim3(MLP_ / 32, DIM_ / 32, DEPTH_), 256, 0, stream>>>(ff_w1, ff1_wt, DIM_, MLP_);
    wconv_kernel<<<dim3(DIM_ / 32, MLP_ / 32, DEPTH_), 256, 0, stream>>>(ff_w2, ff2_wt, MLP_, DIM_);

    xconv_kernel<<<MP_ * IN_DIM_ / 8 / 256, 256, 0, stream>>>(x, x_bf);
    mask_kernel<<<dim3((SP_ + 255) / 256, B_), 256, 0, stream>>>(mask, pbias);

    gemm_bt<64, 1, 0><<<dim3(MP_ / 64, DIM_ / 128), 256, 0, stream>>>(x_bf, proj_wt, proj_b, h, MP_, DIM_, IN_DIM_);
    cls_kernel<<<B_, DIM_, 0, stream>>>(cls_tok, h);

    for (int l = 0; l < DEPTH_; ++l) {
        ln_kernel<<<MP_ / 4, 256, 0, stream>>>(h, ln1_g + l * DIM_, ln1_b + l * DIM_, hn_bf);
        gemm_bt<128, 0, 1><<<dim3(MP_ / 128, 3 * INNER_ / 128), 256, 0, stream>>>(
            hn_bf, qkv_wt + (size_t)l * 3 * INNER_ * DIM_, nullptr, qkv_bf, MP_, 3 * INNER_, DIM_);
        attn_kernel<<<dim3(B_ * HEADS_, SP_ / 128, NCHUNK_), 256, 0, stream>>>(
            qkv_bf, pbias, x_bf, ff1_bf, o_bf, mlbuf);
        attn_combine_kernel<<<dim3(SP_ * 16 / 256, B_ * HEADS_), 256, 0, stream>>>(
            x_bf, ff1_bf, o_bf, mlbuf);
        gemm_bt<64, 0, 0><<<dim3(MP_ / 64, DIM_ / 128), 256, 0, stream>>>(
            o_bf, out_wt + (size_t)l * DIM_ * INNER_, out_b + l * DIM_, h, MP_, DIM_, INNER_);
        ln_kernel<<<MP_ / 4, 256, 0, stream>>>(h, ln2_g + l * DIM_, ln2_b + l * DIM_, hn_bf);
        gemm_bt<64, 2, 1><<<dim3(MP_ / 64, MLP_ / 128), 256, 0, stream>>>(
            hn_bf, ff1_wt + (size_t)l * MLP_ * DIM_, ff_b1 + l * MLP_, ff1_bf, MP_, MLP_, DIM_);
        gemm_bt<64, 0, 0><<<dim3(MP_ / 64, DIM_ / 128), 256, 0, stream>>>(
            ff1_bf, ff2_wt + (size_t)l * DIM_ * MLP_, ff_b2 + l * DIM_, h, MP_, DIM_, MLP_);
    }

    head_kernel<<<B_, 64, 0, stream>>>(h, norm_g, norm_b, hln_g, hln_b, head_w, head_b, (float*)d_out);
}

// Round 4
// 816.717 us; speedup vs baseline: 1.8539x; 1.0558x over previous
//
#include <hip/hip_runtime.h>
#include <hip/hip_bf16.h>
#include <stdint.h>

// ---- problem constants ----
#define B_      2
#define N_      2048
#define S_      2049          // tokens incl. cls
#define SP_     2176          // padded tokens per batch (17*128)
#define MP_     (B_*SP_)      // 4352 = 34*128
#define IN_DIM_ 1024
#define DIM_    512
#define HEADS_  8
#define DH_     128
#define INNER_  1024
#define MLP_    1024
#define DEPTH_  4
#define NKV_    (SP_/64)      // 34
#define NCHUNK_ 4
#define TPC_    9             // KV tiles per chunk (9,9,9,7)

typedef __bf16 bf16;
typedef __bf16 bf16x4 __attribute__((ext_vector_type(4)));
typedef __bf16 bf16x8 __attribute__((ext_vector_type(8)));
typedef float  f32x4  __attribute__((ext_vector_type(4)));

// XOR swizzles (G4/T2). swr: key = (r&7)^((r>>3)&7) works for both row-varying
// and transpose-write lane patterns.
__device__ __forceinline__ int sw64(int r, int c)  { return r*64  + (c ^ ((r&7)<<3)); }
__device__ __forceinline__ int sw128(int r, int c) { return r*128 + (c ^ ((r&7)<<3)); }
__device__ __forceinline__ int swr64(int r, int c) { return r*64  + (c ^ ((((r&7)^((r>>3)&7)))<<3)); }

// ---------------------------------------------------------------------------
// Weight convert + transpose: src [L][K][N] f32 -> dst [L][N][K] bf16
// ---------------------------------------------------------------------------
__global__ __launch_bounds__(256) void wconv_kernel(const float* __restrict__ src,
                                                    bf16* __restrict__ dst,
                                                    int K, int N)
{
    __shared__ float tile[32][33];
    size_t mo = (size_t)blockIdx.z * K * N;
    int n0 = blockIdx.x * 32, k0 = blockIdx.y * 32;
    int tx = threadIdx.x & 31, ty = threadIdx.x >> 5;   // 32 x 8
#pragma unroll
    for (int i = 0; i < 32; i += 8)
        tile[ty + i][tx] = src[mo + (size_t)(k0 + ty + i) * N + n0 + tx];
    __syncthreads();
#pragma unroll
    for (int i = 0; i < 32; i += 8)
        dst[mo + (size_t)(n0 + ty + i) * K + k0 + tx] = (bf16)tile[tx][ty + i];
}

// ---------------------------------------------------------------------------
// x (B,N,IN) f32 -> x_bf (B,SP,IN) bf16 with row 0 + pad rows zeroed
// ---------------------------------------------------------------------------
__global__ __launch_bounds__(256) void xconv_kernel(const float* __restrict__ x,
                                                    bf16* __restrict__ xb)
{
    int idx = blockIdx.x * 256 + threadIdx.x;    // MP_*IN_DIM_/8 items
    int row = idx >> 7;                          // IN_DIM_/8 = 128 groups/row
    int c   = (idx & 127) * 8;
    int b = row / SP_, s = row - b * SP_;
    bf16x8 v;
    if (s >= 1 && s <= N_) {
        const float* src = x + (size_t)(b * N_ + s - 1) * IN_DIM_ + c;
#pragma unroll
        for (int i = 0; i < 8; ++i) v[i] = (bf16)src[i];
    } else {
#pragma unroll
        for (int i = 0; i < 8; ++i) v[i] = (bf16)0.f;
    }
    *(bf16x8*)&xb[(size_t)row * IN_DIM_ + c] = v;
}

// ---------------------------------------------------------------------------
// mask (B,N) -> additive bias pb (B,SP): 0 keep, -1e30 drop (cls always kept)
// ---------------------------------------------------------------------------
__global__ __launch_bounds__(256) void mask_kernel(const float* __restrict__ mask,
                                                   float* __restrict__ pb)
{
    int j = blockIdx.x * 256 + threadIdx.x;
    int b = blockIdx.y;
    if (j >= SP_) return;
    float v;
    if (j == 0) v = 0.f;
    else if (j <= N_) v = (mask[(size_t)b * N_ + j - 1] != 0.f) ? 0.f : -1e30f;
    else v = -1e30f;
    pb[(size_t)b * SP_ + j] = v;
}

// ---------------------------------------------------------------------------
// cls token -> h row 0 of each batch (f32)
// ---------------------------------------------------------------------------
__global__ void cls_kernel(const float* __restrict__ cls, float* __restrict__ h)
{
    h[(size_t)(blockIdx.x * SP_) * DIM_ + threadIdx.x] = cls[threadIdx.x];
}

// ---------------------------------------------------------------------------
// LayerNorm over DIM_=512, one wave per row, f32 in -> bf16 out
// ---------------------------------------------------------------------------
__global__ __launch_bounds__(256) void ln_kernel(const float* __restrict__ h,
                                                 const float* __restrict__ g,
                                                 const float* __restrict__ bta,
                                                 bf16* __restrict__ out)
{
    int row  = blockIdx.x * 4 + (threadIdx.x >> 6);
    int lane = threadIdx.x & 63;
    const float* x = h + (size_t)row * DIM_;
    float v[8]; float s = 0.f;
#pragma unroll
    for (int i = 0; i < 8; ++i) { v[i] = x[lane + 64 * i]; s += v[i]; }
#pragma unroll
    for (int o = 32; o; o >>= 1) s += __shfl_xor(s, o);
    float mean = s * (1.f / DIM_);
    float vs = 0.f;
#pragma unroll
    for (int i = 0; i < 8; ++i) { float d = v[i] - mean; vs += d * d; }
#pragma unroll
    for (int o = 32; o; o >>= 1) vs += __shfl_xor(vs, o);
    float rstd = rsqrtf(vs * (1.f / DIM_) + 1e-5f);
    bf16* orow = out + (size_t)row * DIM_;
#pragma unroll
    for (int i = 0; i < 8; ++i)
        orow[lane + 64 * i] = (bf16)((v[i] - mean) * rstd * g[lane + 64 * i] + bta[lane + 64 * i]);
}

// ---------------------------------------------------------------------------
// GEMM: C[M][N] = act(A[M][K] * Bt[N][K]^T + bias), bf16 in, fp32 acc.
// Tiles: (128,128) 4 waves 64x64; (64,128) 4 waves 64x32; (64,64) 4 waves 32x32.
// BK=64, 256 threads, swizzled LDS, register-prefetch staging (T14-lite).
// ---------------------------------------------------------------------------
template<int BM, int BN, int ACT, int OUTBF>
__global__ __launch_bounds__(256) void gemm_bt(const bf16* __restrict__ A,
                                               const bf16* __restrict__ Bt,
                                               const float* __restrict__ bias,
                                               void* __restrict__ Cp,
                                               int M, int N, int K)
{
    constexpr int MF = (BM == 128) ? 4 : ((BN == 128) ? 4 : 2);
    constexpr int NF = (BM == 128) ? 4 : 2;
    constexpr int AT = BM / 32, BT = BN / 32;
    __shared__ __align__(16) bf16 As[BM * 64];
    __shared__ __align__(16) bf16 Bs[BN * 64];
    const int tid  = threadIdx.x;
    const int wave = tid >> 6, lane = tid & 63;
    const int bm = blockIdx.x * BM, bn = blockIdx.y * BN;
    const int wr = (BM == 128) ? (wave >> 1) * 64 : ((BN == 64) ? (wave >> 1) * 32 : 0);
    const int wc = (BM == 128) ? (wave & 1) * 64 : ((BN == 64) ? (wave & 1) * 32 : wave * 32);
    const int fr = lane & 15, fk = (lane >> 4) * 8;

    f32x4 acc[MF][NF];
#pragma unroll
    for (int m = 0; m < MF; ++m)
#pragma unroll
        for (int n = 0; n < NF; ++n) acc[m][n] = (f32x4){0.f, 0.f, 0.f, 0.f};

    bf16x8 apre[AT], bpre[BT];
    auto ldg = [&](int k0) {
#pragma unroll
        for (int t = 0; t < AT; ++t) {
            int e = (t * 256 + tid) * 8;
            apre[t] = *(const bf16x8*)&A[(size_t)(bm + (e >> 6)) * K + k0 + (e & 63)];
        }
#pragma unroll
        for (int t = 0; t < BT; ++t) {
            int e = (t * 256 + tid) * 8;
            bpre[t] = *(const bf16x8*)&Bt[(size_t)(bn + (e >> 6)) * K + k0 + (e & 63)];
        }
    };

    ldg(0);
    for (int k0 = 0; k0 < K; k0 += 64) {
        __syncthreads();
#pragma unroll
        for (int t = 0; t < AT; ++t) {
            int e = (t * 256 + tid) * 8;
            *(bf16x8*)&As[sw64(e >> 6, e & 63)] = apre[t];
        }
#pragma unroll
        for (int t = 0; t < BT; ++t) {
            int e = (t * 256 + tid) * 8;
            *(bf16x8*)&Bs[sw64(e >> 6, e & 63)] = bpre[t];
        }
        __syncthreads();
        if (k0 + 64 < K) ldg(k0 + 64);   // prefetch flies under the MFMAs
#pragma unroll
        for (int kk = 0; kk < 2; ++kk) {
            bf16x8 af[MF], bb[NF];
#pragma unroll
            for (int m = 0; m < MF; ++m) af[m] = *(const bf16x8*)&As[sw64(wr + m * 16 + fr, kk * 32 + fk)];
#pragma unroll
            for (int n = 0; n < NF; ++n) bb[n] = *(const bf16x8*)&Bs[sw64(wc + n * 16 + fr, kk * 32 + fk)];
#pragma unroll
            for (int m = 0; m < MF; ++m)
#pragma unroll
                for (int n = 0; n < NF; ++n)
                    acc[m][n] = __builtin_amdgcn_mfma_f32_16x16x32_bf16(af[m], bb[n], acc[m][n], 0, 0, 0);
        }
    }

    const int fc = lane & 15, fr4 = (lane >> 4) * 4;
#pragma unroll
    for (int n = 0; n < NF; ++n) {
        int col = bn + wc + n * 16 + fc;
        float bv = bias ? bias[col] : 0.f;
#pragma unroll
        for (int m = 0; m < MF; ++m) {
#pragma unroll
            for (int j = 0; j < 4; ++j) {
                int row = bm + wr + m * 16 + fr4 + j;
                float v = acc[m][n][j] + bv;
                if (ACT == 1) v = fmaxf(v, 0.f);
                if (ACT == 2) v = 0.5f * v * (1.f + erff(v * 0.70710678118654752f));
                if (OUTBF) ((bf16*)Cp)[(size_t)row * N + col] = (bf16)v;
                else       ((float*)Cp)[(size_t)row * N + col] = v;
            }
        }
    }
}

// ---------------------------------------------------------------------------
// Flash attention, KV-split: grid (B*HEADS, SP_/128, NCHUNK_). 4 waves x 32 q.
// P-scratch aliases the K-tile region (3rd barrier) -> 33.5 KB LDS, 4 blk/CU.
// Defer-max (T13, THR=5) skips the O-rescale on max-stable tiles.
// ---------------------------------------------------------------------------
__global__ __launch_bounds__(256) void attn_kernel(const bf16* __restrict__ qkv,
                                                   const float* __restrict__ pb,
                                                   bf16* __restrict__ o0,
                                                   bf16* __restrict__ o1,
                                                   bf16* __restrict__ o2,
                                                   bf16* __restrict__ o3,
                                                   float* __restrict__ mlbuf)
{
    __shared__ __align__(16) bf16 KsPs[64 * 128];   // K-tile, then per-wave P
    __shared__ __align__(16) bf16 Vt[128 * 64];     // [d][j] swizzled (swr)
    __shared__ float Msk[64];

    const int bh = blockIdx.x, b = bh >> 3, hh = bh & 7;
    const int q0 = blockIdx.y * 128;
    const int chunk = blockIdx.z;
    const int t0 = chunk * TPC_;
    const int t1 = (t0 + TPC_ < NKV_) ? t0 + TPC_ : NKV_;
    bf16* obuf = (chunk == 0) ? o0 : (chunk == 1) ? o1 : (chunk == 2) ? o2 : o3;

    const int tid = threadIdx.x, wave = tid >> 6, lane = tid & 63;
    const int fc = lane & 15, g = lane >> 4, g8 = g * 8, rr0 = g * 4;
    bf16* Pw = &KsPs[wave * 2048];      // per-wave 32x64 P scratch (aliases K)

    const bf16* qb = qkv + (size_t)(b * SP_) * (3 * INNER_) + hh * DH_;
    const bf16* kb = qb + INNER_;
    const bf16* vb = qb + 2 * INNER_;

    // Q fragments in registers (B-operand: lane&15 = q, k = g*8+i)
    bf16x8 aq[2][4];
#pragma unroll
    for (int m = 0; m < 2; ++m)
#pragma unroll
        for (int kk = 0; kk < 4; ++kk)
            aq[m][kk] = *(const bf16x8*)&qb[(size_t)(q0 + wave * 32 + m * 16 + fc) * (3 * INNER_) + kk * 32 + g8];

    const int srow = tid >> 4;          // staging: row within 16-row stripe
    const int scol = (tid & 15) * 8;    // staging: 8-elem column
    bf16x8 kreg[4], vreg[4];
    float mreg;

    f32x4 accO[2][8];
#pragma unroll
    for (int m = 0; m < 2; ++m)
#pragma unroll
        for (int f = 0; f < 8; ++f) accO[m][f] = (f32x4){0.f, 0.f, 0.f, 0.f};
    float mrow[2] = {-3e38f, -3e38f};
    float lrow[2] = {0.f, 0.f};
    const float scale = 0.08838834764831845f;   // 1/sqrt(128)

    auto issue = [&](int kt) {          // T14 async stage: global -> regs
        int j0 = kt * 64;
#pragma unroll
        for (int t = 0; t < 4; ++t) {
            kreg[t] = *(const bf16x8*)&kb[(size_t)(j0 + t * 16 + srow) * (3 * INNER_) + scol];
            vreg[t] = *(const bf16x8*)&vb[(size_t)(j0 + t * 16 + srow) * (3 * INNER_) + scol];
        }
        mreg = pb[(size_t)b * SP_ + j0 + (tid & 63)];
    };

    issue(t0);
    for (int kt = t0; kt < t1; ++kt) {
        __syncthreads();          // previous tile fully consumed
        {
#pragma unroll
            for (int t = 0; t < 4; ++t) {
                *(bf16x8*)&KsPs[sw128(t * 16 + srow, scol)] = kreg[t];
#pragma unroll
                for (int i = 0; i < 8; ++i) Vt[swr64(scol + i, t * 16 + srow)] = vreg[t][i];
            }
            if (tid < 64) Msk[tid] = mreg;
        }
        __syncthreads();
        if (kt + 1 < t1) issue(kt + 1);   // loads fly under the compute below

        // ---- S^T = K · Q^T : lane holds S[j = f*16+rr0+r][q = m*16+fc] ----
        f32x4 sf[2][4];
#pragma unroll
        for (int m = 0; m < 2; ++m)
#pragma unroll
            for (int f = 0; f < 4; ++f) sf[m][f] = (f32x4){0.f, 0.f, 0.f, 0.f};
        __builtin_amdgcn_s_setprio(1);
#pragma unroll
        for (int kk = 0; kk < 4; ++kk) {
            bf16x8 bk[4];
#pragma unroll
            for (int f = 0; f < 4; ++f) bk[f] = *(const bf16x8*)&KsPs[sw128(f * 16 + fc, kk * 32 + g8)];
#pragma unroll
            for (int m = 0; m < 2; ++m)
#pragma unroll
                for (int f = 0; f < 4; ++f)
                    sf[m][f] = __builtin_amdgcn_mfma_f32_16x16x32_bf16(bk[f], aq[m][kk], sf[m][f], 0, 0, 0);
        }
        __builtin_amdgcn_s_setprio(0);

        // ---- online softmax (per-q stats live at lane&15 = q) ----
        float rmax[2] = {-3e38f, -3e38f};
#pragma unroll
        for (int f = 0; f < 4; ++f) {
            f32x4 mb = *(const f32x4*)&Msk[f * 16 + rr0];
#pragma unroll
            for (int m = 0; m < 2; ++m)
#pragma unroll
                for (int r = 0; r < 4; ++r) {
                    float s = sf[m][f][r] * scale + mb[r];
                    sf[m][f][r] = s;
                    rmax[m] = fmaxf(rmax[m], s);
                }
        }
#pragma unroll
        for (int m = 0; m < 2; ++m) {
            rmax[m] = fmaxf(rmax[m], __shfl_xor(rmax[m], 16));
            rmax[m] = fmaxf(rmax[m], __shfl_xor(rmax[m], 32));
            // T13 defer-max: only rescale when the max actually grew (> THR)
            if (__any(rmax[m] > mrow[m] + 5.f)) {
                float mn = fmaxf(mrow[m], rmax[m]);
                float corr = __expf(mrow[m] - mn);
                mrow[m] = mn;
                lrow[m] *= corr;
                float c0 = __shfl(corr, rr0 + 0);
                float c1 = __shfl(corr, rr0 + 1);
                float c2 = __shfl(corr, rr0 + 2);
                float c3 = __shfl(corr, rr0 + 3);
#pragma unroll
                for (int f = 0; f < 8; ++f) {
                    accO[m][f][0] *= c0; accO[m][f][1] *= c1;
                    accO[m][f][2] *= c2; accO[m][f][3] *= c3;
                }
            }
        }
        // P = exp(S - m), kept in regs until the QK->P barrier
        bf16x4 pw[2][4];
#pragma unroll
        for (int m = 0; m < 2; ++m)
#pragma unroll
            for (int f = 0; f < 4; ++f) {
#pragma unroll
                for (int r = 0; r < 4; ++r) {
                    float p = __expf(sf[m][f][r] - mrow[m]);
                    lrow[m] += p;
                    pw[m][f][r] = (bf16)p;
                }
            }
        __syncthreads();          // all QK reads of K done -> reuse as P
#pragma unroll
        for (int m = 0; m < 2; ++m)
#pragma unroll
            for (int f = 0; f < 4; ++f)
                *(bf16x4*)&Pw[swr64(m * 16 + fc, f * 16 + rr0)] = pw[m][f];

        // ---- O += P · V ----
        __builtin_amdgcn_s_setprio(1);
#pragma unroll
        for (int kk = 0; kk < 2; ++kk) {
            bf16x8 ap[2];
#pragma unroll
            for (int m = 0; m < 2; ++m) ap[m] = *(const bf16x8*)&Pw[swr64(m * 16 + fc, kk * 32 + g8)];
#pragma unroll
            for (int f = 0; f < 8; ++f) {
                bf16x8 bv = *(const bf16x8*)&Vt[swr64(f * 16 + fc, kk * 32 + g8)];
#pragma unroll
                for (int m = 0; m < 2; ++m)
                    accO[m][f] = __builtin_amdgcn_mfma_f32_16x16x32_bf16(ap[m], bv, accO[m][f], 0, 0, 0);
            }
        }
        __builtin_amdgcn_s_setprio(0);
    }

    // ---- finalize: l-reduce over j-groups, write normalized partial O + (m,l) ----
#pragma unroll
    for (int m = 0; m < 2; ++m) {
        float l = lrow[m];
        l += __shfl_xor(l, 16);
        l += __shfl_xor(l, 32);
        if (g == 0) {   // lanes 0..15 hold stats for q = base + fc
            int q = q0 + wave * 32 + m * 16 + fc;
            size_t mi = ((size_t)(chunk * B_ * HEADS_ + bh) * SP_ + q) * 2;
            mlbuf[mi + 0] = mrow[m];
            mlbuf[mi + 1] = l;
        }
        float linv = (l > 0.f) ? 1.f / l : 0.f;
        float l0 = __shfl(linv, rr0 + 0);
        float l1 = __shfl(linv, rr0 + 1);
        float l2 = __shfl(linv, rr0 + 2);
        float l3 = __shfl(linv, rr0 + 3);
#pragma unroll
        for (int f = 0; f < 8; ++f) {
            int col = hh * DH_ + f * 16 + fc;
            size_t base = (size_t)(b * SP_ + q0 + wave * 32 + m * 16 + rr0) * INNER_ + col;
            obuf[base + 0 * INNER_] = (bf16)(accO[m][f][0] * l0);
            obuf[base + 1 * INNER_] = (bf16)(accO[m][f][1] * l1);
            obuf[base + 2 * INNER_] = (bf16)(accO[m][f][2] * l2);
            obuf[base + 3 * INNER_] = (bf16)(accO[m][f][3] * l3);
        }
    }
}

// ---------------------------------------------------------------------------
// Combine KV-split partials: o_final = sum_c w_c * O_c, w_c = l_c*exp(m_c-M)/den
// grid (SP_*16/256, B*HEADS). o3 is read then overwritten elementwise (safe).
// ---------------------------------------------------------------------------
__global__ __launch_bounds__(256) void attn_combine_kernel(const bf16* __restrict__ o0,
                                                           const bf16* __restrict__ o1,
                                                           const bf16* __restrict__ o2,
                                                           bf16* __restrict__ o3,
                                                           const float* __restrict__ mlbuf)
{
    const int bh = blockIdx.y, b = bh >> 3, hh = bh & 7;
    int gx = blockIdx.x * 256 + threadIdx.x;    // SP_ * 16 items per bh
    int q  = gx >> 4;
    int d  = (gx & 15) * 8;

    float mv[NCHUNK_], lv[NCHUNK_];
#pragma unroll
    for (int c = 0; c < NCHUNK_; ++c) {
        size_t mi = ((size_t)(c * B_ * HEADS_ + bh) * SP_ + q) * 2;
        mv[c] = mlbuf[mi];
        lv[c] = mlbuf[mi + 1];
    }
    float M = mv[0];
#pragma unroll
    for (int c = 1; c < NCHUNK_; ++c) M = fmaxf(M, mv[c]);
    float w[NCHUNK_], den = 0.f;
#pragma unroll
    for (int c = 0; c < NCHUNK_; ++c) { w[c] = lv[c] * __expf(mv[c] - M); den += w[c]; }
    float r = (den > 0.f) ? 1.f / den : 0.f;

    size_t base = (size_t)(b * SP_ + q) * INNER_ + hh * DH_ + d;
    bf16x8 v0 = *(const bf16x8*)&o0[base];
    bf16x8 v1 = *(const bf16x8*)&o1[base];
    bf16x8 v2 = *(const bf16x8*)&o2[base];
    bf16x8 v3 = *(const bf16x8*)&o3[base];
    bf16x8 out;
#pragma unroll
    for (int i = 0; i < 8; ++i)
        out[i] = (bf16)((w[0] * (float)v0[i] + w[1] * (float)v1[i]
                       + w[2] * (float)v2[i] + w[3] * (float)v3[i]) * r);
    *(bf16x8*)&o3[base] = out;
}

// ---------------------------------------------------------------------------
// Head: pooled = h[:,0]; LN(norm) -> LN(head_ln) -> @ head_w + head_b
// ---------------------------------------------------------------------------
__global__ __launch_bounds__(64) void head_kernel(const float* __restrict__ h,
                                                  const float* __restrict__ ng, const float* __restrict__ nb,
                                                  const float* __restrict__ hg, const float* __restrict__ hb,
                                                  const float* __restrict__ hw, const float* __restrict__ hbi,
                                                  float* __restrict__ out)
{
    int b = blockIdx.x, lane = threadIdx.x;
    const float* xr = h + (size_t)(b * SP_) * DIM_;
    float v[8]; float s = 0.f;
#pragma unroll
    for (int i = 0; i < 8; ++i) { v[i] = xr[lane + 64 * i]; s += v[i]; }
#pragma unroll
    for (int o = 32; o; o >>= 1) s += __shfl_xor(s, o);
    float mean = s * (1.f / DIM_); float vs = 0.f;
#pragma unroll
    for (int i = 0; i < 8; ++i) { float d = v[i] - mean; vs += d * d; }
#pragma unroll
    for (int o = 32; o; o >>= 1) vs += __shfl_xor(vs, o);
    float rstd = rsqrtf(vs * (1.f / DIM_) + 1e-5f);
#pragma unroll
    for (int i = 0; i < 8; ++i) v[i] = (v[i] - mean) * rstd * ng[lane + 64 * i] + nb[lane + 64 * i];
    s = 0.f;
#pragma unroll
    for (int i = 0; i < 8; ++i) s += v[i];
#pragma unroll
    for (int o = 32; o; o >>= 1) s += __shfl_xor(s, o);
    mean = s * (1.f / DIM_); vs = 0.f;
#pragma unroll
    for (int i = 0; i < 8; ++i) { float d = v[i] - mean; vs += d * d; }
#pragma unroll
    for (int o = 32; o; o >>= 1) vs += __shfl_xor(vs, o);
    rstd = rsqrtf(vs * (1.f / DIM_) + 1e-5f);
#pragma unroll
    for (int i = 0; i < 8; ++i) v[i] = (v[i] - mean) * rstd * hg[lane + 64 * i] + hb[lane + 64 * i];
    float a0 = 0.f, a1 = 0.f;
#pragma unroll
    for (int i = 0; i < 8; ++i) {
        a0 += v[i] * hw[(lane + 64 * i) * 2 + 0];
        a1 += v[i] * hw[(lane + 64 * i) * 2 + 1];
    }
#pragma unroll
    for (int o = 32; o; o >>= 1) { a0 += __shfl_xor(a0, o); a1 += __shfl_xor(a1, o); }
    if (lane == 0) { out[b * 2 + 0] = a0 + hbi[0]; out[b * 2 + 1] = a1 + hbi[1]; }
}

// ---------------------------------------------------------------------------
extern "C" void kernel_launch(void* const* d_in, const int* in_sizes, int n_in,
                              void* d_out, int out_size, void* d_ws, size_t ws_size,
                              hipStream_t stream)
{
    const float* x       = (const float*)d_in[0];
    const float* mask    = (const float*)d_in[1];
    const float* proj_w  = (const float*)d_in[2];
    const float* proj_b  = (const float*)d_in[3];
    const float* cls_tok = (const float*)d_in[4];
    const float* ln1_g   = (const float*)d_in[5];
    const float* ln1_b   = (const float*)d_in[6];
    const float* qkv_w   = (const float*)d_in[7];
    const float* out_w   = (const float*)d_in[8];
    const float* out_b   = (const float*)d_in[9];
    const float* ln2_g   = (const float*)d_in[10];
    const float* ln2_b   = (const float*)d_in[11];
    const float* ff_w1   = (const float*)d_in[12];
    const float* ff_b1   = (const float*)d_in[13];
    const float* ff_w2   = (const float*)d_in[14];
    const float* ff_b2   = (const float*)d_in[15];
    const float* norm_g  = (const float*)d_in[16];
    const float* norm_b  = (const float*)d_in[17];
    const float* hln_g   = (const float*)d_in[18];
    const float* hln_b   = (const float*)d_in[19];
    const float* head_w  = (const float*)d_in[20];
    const float* head_b  = (const float*)d_in[21];

    char* p = (char*)d_ws;
    auto alloc = [&](size_t bytes) { char* r = p; p += (bytes + 255) & ~(size_t)255; return r; };
    bf16*  x_bf    = (bf16*)alloc((size_t)MP_ * IN_DIM_ * 2);   // dead after proj -> attn chunk0
    float* h       = (float*)alloc((size_t)MP_ * DIM_ * 4);     // dead during attn -> chunk2
    bf16*  hn_bf   = (bf16*)alloc((size_t)MP_ * DIM_ * 2);      // dead during attn -> mlbuf
    bf16*  qkv_bf  = (bf16*)alloc((size_t)MP_ * 3 * INNER_ * 2);
    bf16*  o_bf    = (bf16*)alloc((size_t)MP_ * INNER_ * 2);    // attn chunk3 + final O
    bf16*  ff1_bf  = (bf16*)alloc((size_t)MP_ * MLP_ * 2);      // dead during attn -> chunk1
    bf16*  proj_wt = (bf16*)alloc((size_t)DIM_ * IN_DIM_ * 2);
    bf16*  qkv_wt  = (bf16*)alloc((size_t)DEPTH_ * 3 * INNER_ * DIM_ * 2);
    bf16*  out_wt  = (bf16*)alloc((size_t)DEPTH_ * DIM_ * INNER_ * 2);
    bf16*  ff1_wt  = (bf16*)alloc((size_t)DEPTH_ * MLP_ * DIM_ * 2);
    bf16*  ff2_wt  = (bf16*)alloc((size_t)DEPTH_ * DIM_ * MLP_ * 2);
    float* pbias   = (float*)alloc((size_t)B_ * SP_ * 4);
    if ((size_t)(p - (char*)d_ws) > ws_size) return;
    float* mlbuf = (float*)hn_bf;   // NCHUNK_*16*SP_*2 f32 = 1.1 MB <= 4.45 MB

    // weights -> bf16 [N][K]
    wconv_kernel<<<dim3(DIM_ / 32, IN_DIM_ / 32, 1), 256, 0, stream>>>(proj_w, proj_wt, IN_DIM_, DIM_);
    wconv_kernel<<<dim3(3 * INNER_ / 32, DIM_ / 32, DEPTH_), 256, 0, stream>>>(qkv_w, qkv_wt, DIM_, 3 * INNER_);
    wconv_kernel<<<dim3(DIM_ / 32, INNER_ / 32, DEPTH_), 256, 0, stream>>>(out_w, out_wt, INNER_, DIM_);
    wconv_kernel<<<dim3(MLP_ / 32, DIM_ / 32, DEPTH_), 256, 0, stream>>>(ff_w1, ff1_wt, DIM_, MLP_);
    wconv_kernel<<<dim3(DIM_ / 32, MLP_ / 32, DEPTH_), 256, 0, stream>>>(ff_w2, ff2_wt, MLP_, DIM_);

    xconv_kernel<<<MP_ * IN_DIM_ / 8 / 256, 256, 0, stream>>>(x, x_bf);
    mask_kernel<<<dim3((SP_ + 255) / 256, B_), 256, 0, stream>>>(mask, pbias);

    gemm_bt<64, 64, 1, 0><<<dim3(MP_ / 64, DIM_ / 64), 256, 0, stream>>>(x_bf, proj_wt, proj_b, h, MP_, DIM_, IN_DIM_);
    cls_kernel<<<B_, DIM_, 0, stream>>>(cls_tok, h);

    for (int l = 0; l < DEPTH_; ++l) {
        ln_kernel<<<MP_ / 4, 256, 0, stream>>>(h, ln1_g + l * DIM_, ln1_b + l * DIM_, hn_bf);
        gemm_bt<128, 128, 0, 1><<<dim3(MP_ / 128, 3 * INNER_ / 128), 256, 0, stream>>>(
            hn_bf, qkv_wt + (size_t)l * 3 * INNER_ * DIM_, nullptr, qkv_bf, MP_, 3 * INNER_, DIM_);
        attn_kernel<<<dim3(B_ * HEADS_, SP_ / 128, NCHUNK_), 256, 0, stream>>>(
            qkv_bf, pbias, x_bf, ff1_bf, (bf16*)h, o_bf, mlbuf);
        attn_combine_kernel<<<dim3(SP_ * 16 / 256, B_ * HEADS_), 256, 0, stream>>>(
            x_bf, ff1_bf, (const bf16*)h, o_bf, mlbuf);
        gemm_bt<64, 64, 0, 0><<<dim3(MP_ / 64, DIM_ / 64), 256, 0, stream>>>(
            o_bf, out_wt + (size_t)l * DIM_ * INNER_, out_b + l * DIM_, h, MP_, DIM_, INNER_);
        ln_kernel<<<MP_ / 4, 256, 0, stream>>>(h, ln2_g + l * DIM_, ln2_b + l * DIM_, hn_bf);
        gemm_bt<64, 128, 2, 1><<<dim3(MP_ / 64, MLP_ / 128), 256, 0, stream>>>(
            hn_bf, ff1_wt + (size_t)l * MLP_ * DIM_, ff_b1 + l * MLP_, ff1_bf, MP_, MLP_, DIM_);
        gemm_bt<64, 64, 0, 0><<<dim3(MP_ / 64, DIM_ / 64), 256, 0, stream>>>(
            ff1_bf, ff2_wt + (size_t)l * DIM_ * MLP_, ff_b2 + l * DIM_, h, MP_, DIM_, MLP_);
    }

    head_kernel<<<B_, 64, 0, stream>>>(h, norm_g, norm_b, hln_g, hln_b, head_w, head_b, (float*)d_out);
}